// Round 4
// baseline (494.018 us; speedup 1.0000x reference)
//
#include <hip/hip_runtime.h>
#include <math.h>

#define Bb 4
#define Nn 2048
#define Dd 256
#define Hh 8
#define DHh 32
#define MLPH 1024
#define Ee 262144
#define BNr 8192
#define SD 768          // fused QKV row stride
#define PS 88           // fallback P_lds row stride (ushorts)

#ifndef __has_builtin
#define __has_builtin(x) 0
#endif
#if __has_builtin(__builtin_amdgcn_mfma_f32_16x16x16bf16_1k)
#define HAS_M16 1
#else
#define HAS_M16 0
#endif

typedef __attribute__((ext_vector_type(8))) short bf8;   // 8 bf16 in 4 VGPRs
typedef __attribute__((ext_vector_type(4))) short s4v;   // 4 bf16 in 2 VGPRs
typedef __attribute__((ext_vector_type(4))) float f4;

__device__ __forceinline__ float gelu_f(float x){
  return 0.5f * x * (1.0f + erff(x * 0.70710678118654752f));
}

__device__ __forceinline__ ushort f2bf(float f){
  union { float f; unsigned u; } v; v.f = f;
  unsigned r = v.u + 0x7fffu + ((v.u >> 16) & 1u);   // RNE
  return (ushort)(r >> 16);
}
__device__ __forceinline__ float bf2f(ushort u){
  return __uint_as_float((unsigned)u << 16);
}

// ---------------- edge-index dtype detection ----------------
__global__ void detect_kernel(const int* __restrict__ ei, int* flag){
  __shared__ int nz;
  if (threadIdx.x == 0) nz = 0;
  __syncthreads();
  int any = 0;
  for (int i = threadIdx.x; i < 2048; i += 256)
    if (ei[2*i + 1] != 0) any = 1;
  if (any) atomicOr(&nz, 1);
  __syncthreads();
  if (threadIdx.x == 0) *flag = nz ? 0 : 1;  // 1 => int64 layout
}

__global__ void count_kernel(const int* __restrict__ ei, const int* __restrict__ flag,
                             int* cnt_row, int* cnt_col){
  int e = blockIdx.x * 256 + threadIdx.x;
  if (e >= Ee) return;
  int m = *flag;
  int r = m ? ei[2*e]          : ei[e];
  int c = m ? ei[2*(Ee + e)]   : ei[Ee + e];
  atomicAdd(&cnt_row[r], 1);
  atomicAdd(&cnt_col[c], 1);
}

// exclusive prefix sum of 8192 col-counts + deg^-0.5 of row-counts
__global__ void scan_kernel(const int* __restrict__ cnt, const int* __restrict__ cnt_row,
                            int* start, int* cursor, float* dis){
  __shared__ int part[256];
  int t = threadIdx.x;
  int s = 0;
  for (int i = 0; i < 32; i++) s += cnt[t*32 + i];
  part[t] = s;
  __syncthreads();
  if (t == 0){
    int run = 0;
    for (int i = 0; i < 256; i++){ int tmp = part[i]; part[i] = run; run += tmp; }
    start[BNr] = run;
  }
  __syncthreads();
  int base = part[t];
  for (int i = 0; i < 32; i++){
    start[t*32 + i]  = base;
    cursor[t*32 + i] = base;
    base += cnt[t*32 + i];
  }
  for (int i = t; i < BNr; i += 256){
    int d = cnt_row[i];
    dis[i] = d > 0 ? 1.0f / sqrtf((float)d) : 0.0f;
  }
}

__global__ void fill_kernel(const int* __restrict__ ei, const int* __restrict__ flag,
                            int* cursor, int* bucket){
  int e = blockIdx.x * 256 + threadIdx.x;
  if (e >= Ee) return;
  int m = *flag;
  int c = m ? ei[2*(Ee + e)] : ei[Ee + e];
  int p = atomicAdd(&cursor[c], 1);
  bucket[p] = e;
}

// ---------------- converts ----------------
__global__ void conv_kernel(const float* __restrict__ src, ushort* __restrict__ dst, int n4){
  int i = blockIdx.x * 256 + threadIdx.x;
  if (i < n4){
    float4 v = ((const float4*)src)[i];
    ushort4 o;
    o.x = f2bf(v.x); o.y = f2bf(v.y); o.z = f2bf(v.z); o.w = f2bf(v.w);
    ((ushort4*)dst)[i] = o;
  }
}

// transpose-convert fp32 [R][C] -> bf16 [C][R]
__device__ __forceinline__ void tconv_body(const float* src, ushort* dst, int R, int C){
  __shared__ float tile[32][33];
  int c0 = blockIdx.x * 32, r0 = blockIdx.y * 32;
  int tx = threadIdx.x & 31, ty = threadIdx.x >> 5;
  for (int i = ty; i < 32; i += 8)
    tile[i][tx] = src[(size_t)(r0 + i) * C + c0 + tx];
  __syncthreads();
  for (int i = ty; i < 32; i += 8)
    dst[(size_t)(c0 + i) * R + r0 + tx] = f2bf(tile[tx][i]);
}

__global__ void tconv_kernel(const float* __restrict__ src, ushort* __restrict__ dst, int R, int C){
  tconv_body(src, dst, R, C);
}

__global__ void tconv5_kernel(const float* s0, const float* s1, const float* s2,
                              const float* s3, const float* s4,
                              ushort* d0, ushort* d1, ushort* d2, ushort* d3, ushort* d4){
  const float* s; ushort* d;
  switch (blockIdx.z){
    case 0: s = s0; d = d0; break;
    case 1: s = s1; d = d1; break;
    case 2: s = s2; d = d2; break;
    case 3: s = s3; d = d3; break;
    default: s = s4; d = d4; break;
  }
  tconv_body(s, d, 256, 256);
}

__global__ void bias_cat_kernel(const float* __restrict__ bq, const float* __restrict__ bk,
                                const float* __restrict__ bv, float* __restrict__ o){
  int i = blockIdx.x * 256 + threadIdx.x;
  if (i < 256) o[i] = bq[i];
  else if (i < 512) o[i] = bk[i - 256];
  else if (i < 768) o[i] = bv[i - 512];
}

// V slice of fused QKV -> Vt global [b*H+h][32 dh][2048 n]
__global__ void vt_kernel(const ushort* __restrict__ QKV, ushort* __restrict__ VtG){
  __shared__ ushort tile[32][33];
  int n0 = blockIdx.x * 32, bh = blockIdx.y;
  int b = bh >> 3, h = bh & 7;
  int tx = threadIdx.x & 31, ty = threadIdx.x >> 5;
  for (int i = ty; i < 32; i += 8)
    tile[i][tx] = QKV[(size_t)(b*Nn + n0 + i)*SD + 512 + h*DHh + tx];
  __syncthreads();
  for (int i = ty; i < 32; i += 8)
    VtG[(size_t)bh*DHh*Nn + (size_t)i*Nn + n0 + tx] = tile[tx][i];
}

// K slice of fused QKV -> Kp global [b*H+h][2048 n][32 dh]
__global__ void kp_kernel(const ushort* __restrict__ QKV, ushort* __restrict__ Kp){
  int tid = blockIdx.x * 256 + threadIdx.x;   // 524288 total, one ushort4 each
  int dh4 = tid & 7, n = (tid >> 3) & 2047, bh = tid >> 14;
  int b = bh >> 3, h = bh & 7;
  ushort4 v = *(const ushort4*)&QKV[(size_t)(b*Nn + n)*SD + 256 + h*DHh + dh4*4];
  *(ushort4*)&Kp[(size_t)bh*Nn*DHh + (size_t)n*DHh + dh4*4] = v;
}

// ---------------- GraphConv gather (bf16 xt) + residual + LN1 ----------------
__global__ __launch_bounds__(256) void gather_ln_kernel(
    const ushort* __restrict__ xtb, const int* __restrict__ ei, const int* __restrict__ flag,
    const int* __restrict__ start, const int* __restrict__ bucket,
    const float* __restrict__ dis, const float* __restrict__ x,
    const float* __restrict__ gc_b, const float* __restrict__ gamma,
    const float* __restrict__ beta, float* __restrict__ out, ushort* __restrict__ outb){
  int v = blockIdx.x, t = threadIdx.x;
  int m = *flag;
  int s0 = start[v], s1 = start[v+1];
  float dv = dis[v];
  float acc = 0.f;
  for (int ii = s0; ii < s1; ii++){
    int e = bucket[ii];
    int r = m ? ei[2*e] : ei[e];
    float nrm = dv * dis[r];
    acc += nrm * bf2f(xtb[(size_t)r*Dd + t]);
  }
  float val = x[(size_t)v*Dd + t] + acc + gc_b[t];

  float s = val;
  #pragma unroll
  for (int o = 32; o > 0; o >>= 1) s += __shfl_xor(s, o);
  __shared__ float wsum[4], wsum2[4];
  int wid = t >> 6, lane = t & 63;
  if (lane == 0) wsum[wid] = s;
  __syncthreads();
  float mu = (wsum[0]+wsum[1]+wsum[2]+wsum[3]) * (1.0f/Dd);
  float dvl = val - mu;
  float s2 = dvl*dvl;
  #pragma unroll
  for (int o = 32; o > 0; o >>= 1) s2 += __shfl_xor(s2, o);
  if (lane == 0) wsum2[wid] = s2;
  __syncthreads();
  float var = (wsum2[0]+wsum2[1]+wsum2[2]+wsum2[3]) * (1.0f/Dd);
  float res = dvl * rsqrtf(var + 1e-5f) * gamma[t] + beta[t];
  out[(size_t)v*Dd + t] = res;
  outb[(size_t)v*Dd + t] = f2bf(res);
}

__global__ __launch_bounds__(256) void add_ln_kernel(
    const float* __restrict__ a, const float* __restrict__ b,
    const float* __restrict__ gamma, const float* __restrict__ beta,
    float* __restrict__ out, ushort* __restrict__ outb){
  int row = blockIdx.x, t = threadIdx.x;
  size_t off = (size_t)row*Dd + t;
  float val = a[off] + b[off];

  float s = val;
  #pragma unroll
  for (int o = 32; o > 0; o >>= 1) s += __shfl_xor(s, o);
  __shared__ float wsum[4], wsum2[4];
  int wid = t >> 6, lane = t & 63;
  if (lane == 0) wsum[wid] = s;
  __syncthreads();
  float mu = (wsum[0]+wsum[1]+wsum[2]+wsum[3]) * (1.0f/Dd);
  float dvl = val - mu;
  float s2 = dvl*dvl;
  #pragma unroll
  for (int o = 32; o > 0; o >>= 1) s2 += __shfl_xor(s2, o);
  if (lane == 0) wsum2[wid] = s2;
  __syncthreads();
  float var = (wsum2[0]+wsum2[1]+wsum2[2]+wsum2[3]) * (1.0f/Dd);
  float res = dvl * rsqrtf(var + 1e-5f) * gamma[t] + beta[t];
  out[off] = res;
  if (outb) outb[off] = f2bf(res);
}

// ---------------- bf16 MFMA GEMM, 128x64 tile (for N>=768) ----------------
#define LDA_S 56

template<int OB, int ACT>
__global__ __launch_bounds__(256,2) void gemm_bf16(
    const ushort* __restrict__ A, const ushort* __restrict__ Bt,
    const float* __restrict__ bias, float* __restrict__ Cf, ushort* __restrict__ Cb,
    int M, int K, int N, int scale_cols, float scalev){
  __shared__ ushort As[2][128*LDA_S];
  __shared__ ushort Bs[2][64*LDA_S];
  int t = threadIdx.x;
  int lane = t & 63, wid = t >> 6;
  int wm = wid >> 1, wn = wid & 1;
  int l15 = lane & 15, lg = lane >> 4;
  int m0 = blockIdx.y * 128, n0 = blockIdx.x * 64;

  int sr = t >> 2;
  int sk = (t & 3) * 8;
  const ushort* Ag1 = A  + (size_t)(m0 + sr) * K + sk;
  const ushort* Ag2 = A  + (size_t)(m0 + 64 + sr) * K + sk;
  const ushort* Bg  = Bt + (size_t)(n0 + sr) * K + sk;

  int nsteps = K / 32;
  bf8 ra1 = *(const bf8*)Ag1;
  bf8 ra2 = *(const bf8*)Ag2;
  bf8 rb  = *(const bf8*)Bg;
  *(bf8*)&As[0][sr*LDA_S + sk]        = ra1;
  *(bf8*)&As[0][(64+sr)*LDA_S + sk]   = ra2;
  *(bf8*)&Bs[0][sr*LDA_S + sk]        = rb;
  __syncthreads();

  f4 acc[4][2] = {};
  for (int ks = 0; ks < nsteps; ks++){
    int cur = ks & 1;
    if (ks + 1 < nsteps){
      ra1 = *(const bf8*)(Ag1 + (ks+1)*32);
      ra2 = *(const bf8*)(Ag2 + (ks+1)*32);
      rb  = *(const bf8*)(Bg  + (ks+1)*32);
    }
    bf8 af[4], bfr[2];
    #pragma unroll
    for (int mf = 0; mf < 4; mf++)
      af[mf] = *(bf8*)&As[cur][(wm*64 + mf*16 + l15)*LDA_S + lg*8];
    #pragma unroll
    for (int nf = 0; nf < 2; nf++)
      bfr[nf] = *(bf8*)&Bs[cur][(wn*32 + nf*16 + l15)*LDA_S + lg*8];
    #pragma unroll
    for (int mf = 0; mf < 4; mf++)
      #pragma unroll
      for (int nf = 0; nf < 2; nf++)
        acc[mf][nf] = __builtin_amdgcn_mfma_f32_16x16x32_bf16(af[mf], bfr[nf], acc[mf][nf], 0, 0, 0);
    __syncthreads();
    if (ks + 1 < nsteps){
      int nxt = cur ^ 1;
      *(bf8*)&As[nxt][sr*LDA_S + sk]      = ra1;
      *(bf8*)&As[nxt][(64+sr)*LDA_S + sk] = ra2;
      *(bf8*)&Bs[nxt][sr*LDA_S + sk]      = rb;
      __syncthreads();
    }
  }

  #pragma unroll
  for (int mf = 0; mf < 4; mf++){
    int row = m0 + wm*64 + mf*16 + lg*4;
    #pragma unroll
    for (int nf = 0; nf < 2; nf++){
      int col = n0 + wn*32 + nf*16 + l15;
      float bv = bias ? bias[col] : 0.f;
      #pragma unroll
      for (int r = 0; r < 4; r++){
        float v = acc[mf][nf][r] + bv;
        if (col < scale_cols) v *= scalev;
        if (ACT) v = gelu_f(v);
        if (OB) Cb[(size_t)(row + r) * N + col] = f2bf(v);
        else    Cf[(size_t)(row + r) * N + col] = v;
      }
    }
  }
}

// ---------------- bf16 MFMA GEMM, 64x64 tile (for N=256: 512 blocks) --------
template<int OB, int ACT>
__global__ __launch_bounds__(256,4) void gemm64_bf16(
    const ushort* __restrict__ A, const ushort* __restrict__ Bt,
    const float* __restrict__ bias, float* __restrict__ Cf, ushort* __restrict__ Cb,
    int M, int K, int N, int scale_cols, float scalev){
  __shared__ ushort As[2][64*LDA_S];
  __shared__ ushort Bs[2][64*LDA_S];
  int t = threadIdx.x;
  int lane = t & 63, wid = t >> 6;
  int wm = wid >> 1, wn = wid & 1;
  int l15 = lane & 15, lg = lane >> 4;
  int m0 = blockIdx.y * 64, n0 = blockIdx.x * 64;
  int sr = t >> 2, sk = (t & 3) * 8;
  const ushort* Ag = A  + (size_t)(m0 + sr) * K + sk;
  const ushort* Bg = Bt + (size_t)(n0 + sr) * K + sk;
  int nsteps = K / 32;
  bf8 ra = *(const bf8*)Ag;
  bf8 rb = *(const bf8*)Bg;
  *(bf8*)&As[0][sr*LDA_S + sk] = ra;
  *(bf8*)&Bs[0][sr*LDA_S + sk] = rb;
  __syncthreads();
  f4 acc[2][2] = {};
  for (int ks = 0; ks < nsteps; ks++){
    int cur = ks & 1;
    if (ks + 1 < nsteps){
      ra = *(const bf8*)(Ag + (ks+1)*32);
      rb = *(const bf8*)(Bg + (ks+1)*32);
    }
    bf8 af[2], bfr[2];
    #pragma unroll
    for (int mf = 0; mf < 2; mf++)
      af[mf] = *(bf8*)&As[cur][(wm*32 + mf*16 + l15)*LDA_S + lg*8];
    #pragma unroll
    for (int nf = 0; nf < 2; nf++)
      bfr[nf] = *(bf8*)&Bs[cur][(wn*32 + nf*16 + l15)*LDA_S + lg*8];
    #pragma unroll
    for (int mf = 0; mf < 2; mf++)
      #pragma unroll
      for (int nf = 0; nf < 2; nf++)
        acc[mf][nf] = __builtin_amdgcn_mfma_f32_16x16x32_bf16(af[mf], bfr[nf], acc[mf][nf], 0, 0, 0);
    __syncthreads();
    if (ks + 1 < nsteps){
      int nxt = cur ^ 1;
      *(bf8*)&As[nxt][sr*LDA_S + sk] = ra;
      *(bf8*)&Bs[nxt][sr*LDA_S + sk] = rb;
      __syncthreads();
    }
  }
  #pragma unroll
  for (int mf = 0; mf < 2; mf++){
    int row = m0 + wm*32 + mf*16 + lg*4;
    #pragma unroll
    for (int nf = 0; nf < 2; nf++){
      int col = n0 + wn*32 + nf*16 + l15;
      float bv = bias ? bias[col] : 0.f;
      #pragma unroll
      for (int r = 0; r < 4; r++){
        float v = acc[mf][nf][r] + bv;
        if (col < scale_cols) v *= scalev;
        if (ACT) v = gelu_f(v);
        if (OB) Cb[(size_t)(row + r) * N + col] = f2bf(v);
        else    Cf[(size_t)(row + r) * N + col] = v;
      }
    }
  }
}

// ---------------- MFMA flash attention v3: barrier-free, P-in-register ------
// block: (b,h, 64 q rows); 4 independent waves x 16 q. Q pre-scaled by
// log2(e)/sqrt(32) in the QKV GEMM; softmax in exp2 domain; defer-max THR=11.
__global__ __launch_bounds__(256,4) void attn3_kernel(
    const ushort* __restrict__ QKV, const ushort* __restrict__ Kp,
    const ushort* __restrict__ VtG, ushort* __restrict__ AO){
#if !HAS_M16
  __shared__ ushort Pl[4][16*PS];   // wave-private, no barrier needed
#endif
  int bh = blockIdx.x >> 5, qb = blockIdx.x & 31;
  int b = bh >> 3, h = bh & 7;
  const ushort* Qg = QKV + (size_t)(b*Nn)*SD + h*DHh;
  const ushort* Kh = Kp  + (size_t)bh*Nn*DHh;
  const ushort* Vh = VtG + (size_t)bh*DHh*Nn;
  int t = threadIdx.x;
  int lane = t & 63, wid = t >> 6;
  int l15 = lane & 15, lg = lane >> 4;
  int q0 = qb*64 + wid*16;

  bf8 qf = *(const bf8*)&Qg[(size_t)(q0 + l15)*SD + lg*8];

  float m_st = -1e30f, l_st = 0.f;
  f4 oacc[2] = {};

  for (int k0 = 0; k0 < Nn; k0 += 64){
    // swapped QK^T: D[key][q]; lane holds 16 scores for q=l15, key=kt*16+lg*4+r
    f4 s[4] = {};
    #pragma unroll
    for (int kt = 0; kt < 4; kt++){
      bf8 kf = *(const bf8*)&Kh[(size_t)(k0 + kt*16 + l15)*DHh + lg*8];
      s[kt] = __builtin_amdgcn_mfma_f32_16x16x32_bf16(kf, qf, s[kt], 0, 0, 0);
    }

    float mx = s[0][0];
    #pragma unroll
    for (int kt = 0; kt < 4; kt++)
      #pragma unroll
      for (int r = 0; r < 4; r++)
        mx = fmaxf(mx, s[kt][r]);
    if (__any(mx > m_st + 11.0f)){     // defer-max: rarely taken after chunk 0
      float mw = fmaxf(mx, __shfl_xor(mx, 16));
      mw = fmaxf(mw, __shfl_xor(mw, 32));
      float Mn = fmaxf(m_st, mw);
      float corr = exp2f(m_st - Mn);
      l_st *= corr;
      #pragma unroll
      for (int r = 0; r < 4; r++){
        float cr = __shfl(corr, (lane & 48) | (lg*4 + r));
        oacc[0][r] *= cr;
        oacc[1][r] *= cr;
      }
      m_st = Mn;
    }

    float ps = 0.f;
    ushort hp[4][4];
    #pragma unroll
    for (int kt = 0; kt < 4; kt++)
      #pragma unroll
      for (int r = 0; r < 4; r++){
        float p = exp2f(s[kt][r] - m_st);
        unsigned pb = __float_as_uint(p) & 0xffff0000u;  // trunc-to-bf16 (p>=0)
        hp[kt][r] = (ushort)(pb >> 16);
        ps += __uint_as_float(pb);                        // consistent with PV
      }
    ps += __shfl_xor(ps, 16);
    ps += __shfl_xor(ps, 32);
    l_st += ps;

#if HAS_M16
    // PV via 16x16x16: P already in A-frag layout (k = lg*4 + i). Zero moves.
    #pragma unroll
    for (int kt = 0; kt < 4; kt++){
      s4v pa;
      pa[0] = (short)hp[kt][0]; pa[1] = (short)hp[kt][1];
      pa[2] = (short)hp[kt][2]; pa[3] = (short)hp[kt][3];
      #pragma unroll
      for (int nt = 0; nt < 2; nt++){
        s4v vf = *(const s4v*)&Vh[(size_t)(nt*16 + l15)*Nn + k0 + kt*16 + lg*4];
        oacc[nt] = __builtin_amdgcn_mfma_f32_16x16x16bf16_1k(pa, vf, oacc[nt], 0, 0, 0);
      }
    }
#else
    // fallback: wave-private LDS re-layout + 16x16x32
    ushort* Pw = Pl[wid];
    #pragma unroll
    for (int kt = 0; kt < 4; kt++){
      ushort4 pk = { hp[kt][0], hp[kt][1], hp[kt][2], hp[kt][3] };
      *(ushort4*)&Pw[l15*PS + kt*16 + lg*4] = pk;
    }
    #pragma unroll
    for (int ksb = 0; ksb < 2; ksb++){
      bf8 pf = *(bf8*)&Pw[l15*PS + ksb*32 + lg*8];
      #pragma unroll
      for (int nt = 0; nt < 2; nt++){
        bf8 vf = *(const bf8*)&Vh[(size_t)(nt*16 + l15)*Nn + k0 + ksb*32 + lg*8];
        oacc[nt] = __builtin_amdgcn_mfma_f32_16x16x32_bf16(pf, vf, oacc[nt], 0, 0, 0);
      }
    }
#endif
  }

  float invl = 1.0f / l_st;
  #pragma unroll
  for (int r = 0; r < 4; r++){
    float il = __shfl(invl, (lane & 48) | (lg*4 + r));
    int row = b*Nn + q0 + lg*4 + r;
    #pragma unroll
    for (int nt = 0; nt < 2; nt++)
      AO[(size_t)row*Dd + h*DHh + nt*16 + l15] = f2bf(oacc[nt][r] * il);
  }
}

extern "C" void kernel_launch(void* const* d_in, const int* in_sizes, int n_in,
                              void* d_out, int out_size, void* d_ws, size_t ws_size,
                              hipStream_t stream){
  const float* x      = (const float*)d_in[0];
  const int*   ei     = (const int*)d_in[1];
  const float* gc_w   = (const float*)d_in[2];
  const float* gc_b   = (const float*)d_in[3];
  const float* g_gamma= (const float*)d_in[4];
  const float* g_beta = (const float*)d_in[5];
  const float* wq = (const float*)d_in[6];  const float* bq = (const float*)d_in[7];
  const float* wk = (const float*)d_in[8];  const float* bk = (const float*)d_in[9];
  const float* wv = (const float*)d_in[10]; const float* bv = (const float*)d_in[11];
  const float* wo = (const float*)d_in[12]; const float* bo = (const float*)d_in[13];
  const float* a_gamma = (const float*)d_in[14]; const float* a_beta = (const float*)d_in[15];
  const float* w1 = (const float*)d_in[16]; const float* b1 = (const float*)d_in[17];
  const float* w2 = (const float*)d_in[18]; const float* b2 = (const float*)d_in[19];
  const float* m_gamma = (const float*)d_in[20]; const float* m_beta = (const float*)d_in[21];
  float* out = (float*)d_out;

  const size_t S = (size_t)BNr * Dd;   // 2,097,152

  char* p = (char*)d_ws;
  auto alloc = [&](size_t bytes){ char* r = p; p += (bytes + 255) & ~(size_t)255; return r; };

  float* X1    = (float*)alloc(S * 4);
  float* X2    = (float*)alloc(S * 4);
  float* MO    = (float*)alloc(S * 4);
  ushort* QKVb = (ushort*)alloc((size_t)BNr * SD * 2);   // PROJ aliases front
  ushort* regA = (ushort*)alloc(S * 2);   // xbf then AOb
  ushort* regB = (ushort*)alloc(S * 2);   // XTb then X2b
  ushort* X1b  = (ushort*)alloc(S * 2);
  ushort* VtG  = (ushort*)alloc(S * 2);
  ushort* Kp   = (ushort*)alloc(S * 2);
  ushort* Hb   = (ushort*)alloc((size_t)BNr * MLPH * 2);
  ushort* gcwT = (ushort*)alloc(65536 * 2);
  ushort* wqkvT= (ushort*)alloc((size_t)SD * 256 * 2);
  ushort* woT  = (ushort*)alloc(65536 * 2);
  ushort* w1T  = (ushort*)alloc(262144 * 2);
  ushort* w2T  = (ushort*)alloc(262144 * 2);
  float* bqkv  = (float*)alloc(SD * 4);
  int* cnt_row = (int*)alloc(8192 * 4);
  int* cnt_col = (int*)alloc(8192 * 4);
  int* startA  = (int*)alloc(8200 * 4);
  int* cursor  = (int*)alloc(8192 * 4);
  int* bucket  = (int*)alloc(Ee * 4);
  float* dis   = (float*)alloc(8192 * 4);
  int* flag    = (int*)alloc(256);

  ushort* xbf = regA;  ushort* AOb = regA;
  ushort* XTb = regB;  ushort* X2b = regB;
  float*  PROJ = (float*)QKVb;

  hipMemsetAsync(cnt_row, 0, 8192 * sizeof(int), stream);
  hipMemsetAsync(cnt_col, 0, 8192 * sizeof(int), stream);

  // graph prep
  detect_kernel<<<1, 256, 0, stream>>>(ei, flag);
  count_kernel<<<Ee/256, 256, 0, stream>>>(ei, flag, cnt_row, cnt_col);
  scan_kernel<<<1, 256, 0, stream>>>(cnt_col, cnt_row, startA, cursor, dis);
  fill_kernel<<<Ee/256, 256, 0, stream>>>(ei, flag, cursor, bucket);

  // converts
  conv_kernel<<<(int)(S/4/256), 256, 0, stream>>>(x, xbf, (int)(S/4));
  tconv5_kernel<<<dim3(8,8,5), 256, 0, stream>>>(gc_w, wq, wk, wv, wo,
      gcwT, wqkvT, wqkvT + 65536, wqkvT + 131072, woT);
  tconv_kernel<<<dim3(32,8), 256, 0, stream>>>(w1, w1T, 256, 1024);
  tconv_kernel<<<dim3(8,32), 256, 0, stream>>>(w2, w2T, 1024, 256);
  bias_cat_kernel<<<3, 256, 0, stream>>>(bq, bk, bv, bqkv);

  const float qscale = 0.17677669529663687f * 1.4426950408889634f;  // log2e/sqrt(32)

  // xt = x @ gc_w  (bf16 out)
  gemm64_bf16<1,0><<<dim3(Dd/64, BNr/64), 256, 0, stream>>>(
      xbf, gcwT, nullptr, nullptr, XTb, BNr, Dd, Dd, 0, 1.0f);
  // GraphConv gather + residual + LN1
  gather_ln_kernel<<<BNr, 256, 0, stream>>>(XTb, ei, flag, startA, bucket, dis,
                                            x, gc_b, g_gamma, g_beta, X1, X1b);
  // fused QKV (Q pre-scaled into exp2 domain)
  gemm_bf16<1,0><<<dim3(SD/64, BNr/128), 256, 0, stream>>>(
      X1b, wqkvT, bqkv, nullptr, QKVb, BNr, Dd, SD, 256, qscale);
  // per-head packed K and transposed V
  kp_kernel<<<2048, 256, 0, stream>>>(QKVb, Kp);
  vt_kernel<<<dim3(Nn/32, Bb*Hh), 256, 0, stream>>>(QKVb, VtG);
  // attention (barrier-free)
  attn3_kernel<<<Bb*Hh*32, 256, 0, stream>>>(QKVb, Kp, VtG, AOb);
  // out proj (fp32, aliases QKVb) + LN2
  gemm64_bf16<0,0><<<dim3(Dd/64, BNr/64), 256, 0, stream>>>(
      AOb, woT, bo, PROJ, nullptr, BNr, Dd, Dd, 0, 1.0f);
  add_ln_kernel<<<BNr, 256, 0, stream>>>(X1, PROJ, a_gamma, a_beta, X2, X2b);
  // MLP
  gemm_bf16<1,1><<<dim3(MLPH/64, BNr/128), 256, 0, stream>>>(
      X2b, w1T, b1, nullptr, Hb, BNr, Dd, MLPH, 0, 1.0f);
  gemm64_bf16<0,0><<<dim3(Dd/64, BNr/64), 256, 0, stream>>>(
      Hb, w2T, b2, MO, nullptr, BNr, MLPH, Dd, 0, 1.0f);
  add_ln_kernel<<<BNr, 256, 0, stream>>>(X2, MO, m_gamma, m_beta, out, nullptr);
}

// Round 5
// 357.065 us; speedup vs baseline: 1.3836x; 1.3836x over previous
//
#include <hip/hip_runtime.h>
#include <math.h>

#define Bb 4
#define Nn 2048
#define Dd 256
#define Hh 8
#define DHh 32
#define MLPH 1024
#define Ee 262144
#define BNr 8192
#define KS_S 40        // K LDS row stride (ushorts) = 80B, mult of 16
#define VT_S 72        // Vt LDS row stride = 144B
#define PS 72          // P LDS row stride = 144B

typedef __attribute__((ext_vector_type(8))) short bf8;   // 8 bf16 in 4 VGPRs
typedef __attribute__((ext_vector_type(4))) float f4;

__device__ __forceinline__ float gelu_f(float x){
  return 0.5f * x * (1.0f + erff(x * 0.70710678118654752f));
}

__device__ __forceinline__ ushort f2bf(float f){
  union { float f; unsigned u; } v; v.f = f;
  unsigned r = v.u + 0x7fffu + ((v.u >> 16) & 1u);   // RNE
  return (ushort)(r >> 16);
}
__device__ __forceinline__ float bf2f(ushort u){
  return __uint_as_float((unsigned)u << 16);
}

// ---------------- edge-index dtype detection ----------------
__global__ void detect_kernel(const int* __restrict__ ei, int* flag){
  __shared__ int nz;
  if (threadIdx.x == 0) nz = 0;
  __syncthreads();
  int any = 0;
  for (int i = threadIdx.x; i < 2048; i += 256)
    if (ei[2*i + 1] != 0) any = 1;
  if (any) atomicOr(&nz, 1);
  __syncthreads();
  if (threadIdx.x == 0) *flag = nz ? 0 : 1;  // 1 => int64 layout
}

__global__ void count_kernel(const int* __restrict__ ei, const int* __restrict__ flag,
                             int* cnt_row, int* cnt_col){
  int e = blockIdx.x * 256 + threadIdx.x;
  if (e >= Ee) return;
  int m = *flag;
  int r = m ? ei[2*e]          : ei[e];
  int c = m ? ei[2*(Ee + e)]   : ei[Ee + e];
  atomicAdd(&cnt_row[r], 1);
  atomicAdd(&cnt_col[c], 1);
}

// exclusive prefix sum of col-counts + deg^-0.5 of row-counts
__global__ void scan_kernel(const int* __restrict__ cnt, const int* __restrict__ cnt_row,
                            int* start, int* cursor, float* dis){
  __shared__ int part[256];
  int t = threadIdx.x;
  int s = 0;
  for (int i = 0; i < 32; i++) s += cnt[t*32 + i];
  part[t] = s;
  __syncthreads();
  if (t == 0){
    int run = 0;
    for (int i = 0; i < 256; i++){ int tmp = part[i]; part[i] = run; run += tmp; }
    start[BNr] = run;
  }
  __syncthreads();
  int base = part[t];
  for (int i = 0; i < 32; i++){
    start[t*32 + i]  = base;
    cursor[t*32 + i] = base;
    base += cnt[t*32 + i];
  }
  for (int i = t; i < BNr; i += 256){
    int d = cnt_row[i];
    dis[i] = d > 0 ? 1.0f / sqrtf((float)d) : 0.0f;
  }
}

// bucket edges by destination; store source row and premultiplied norm
__global__ void fill_kernel(const int* __restrict__ ei, const int* __restrict__ flag,
                            const float* __restrict__ dis,
                            int* cursor, int* bucketR, float* bucketN){
  int e = blockIdx.x * 256 + threadIdx.x;
  if (e >= Ee) return;
  int m = *flag;
  int r = m ? ei[2*e]        : ei[e];
  int c = m ? ei[2*(Ee + e)] : ei[Ee + e];
  int p = atomicAdd(&cursor[c], 1);
  bucketR[p] = r;
  bucketN[p] = dis[r] * dis[c];
}

// ---------------- converts ----------------
__global__ void conv_kernel(const float* __restrict__ src, ushort* __restrict__ dst, int n4){
  int i = blockIdx.x * 256 + threadIdx.x;
  if (i < n4){
    float4 v = ((const float4*)src)[i];
    ushort4 o;
    o.x = f2bf(v.x); o.y = f2bf(v.y); o.z = f2bf(v.z); o.w = f2bf(v.w);
    ((ushort4*)dst)[i] = o;
  }
}

// transpose-convert fp32 [R][C] -> bf16 [C][R]
__device__ __forceinline__ void tconv_body(const float* src, ushort* dst, int R, int C){
  __shared__ float tile[32][33];
  int c0 = blockIdx.x * 32, r0 = blockIdx.y * 32;
  int tx = threadIdx.x & 31, ty = threadIdx.x >> 5;
  for (int i = ty; i < 32; i += 8)
    tile[i][tx] = src[(size_t)(r0 + i) * C + c0 + tx];
  __syncthreads();
  for (int i = ty; i < 32; i += 8)
    dst[(size_t)(c0 + i) * R + r0 + tx] = f2bf(tile[tx][i]);
}

__global__ void tconv_kernel(const float* __restrict__ src, ushort* __restrict__ dst, int R, int C){
  tconv_body(src, dst, R, C);
}

__global__ void tconv5_kernel(const float* s0, const float* s1, const float* s2,
                              const float* s3, const float* s4,
                              ushort* d0, ushort* d1, ushort* d2, ushort* d3, ushort* d4){
  const float* s; ushort* d;
  switch (blockIdx.z){
    case 0: s = s0; d = d0; break;
    case 1: s = s1; d = d1; break;
    case 2: s = s2; d = d2; break;
    case 3: s = s3; d = d3; break;
    default: s = s4; d = d4; break;
  }
  tconv_body(s, d, 256, 256);
}

__global__ void bias_cat_kernel(const float* __restrict__ bq, const float* __restrict__ bk,
                                const float* __restrict__ bv, float* __restrict__ o){
  int i = blockIdx.x * 256 + threadIdx.x;
  if (i < 256) o[i] = bq[i];
  else if (i < 512) o[i] = bk[i - 256];
  else if (i < 768) o[i] = bv[i - 512];
}

// Vtmp [BN][256] -> VtG [b*H+h][32 dh][2048 n]
__global__ void vt_kernel(const ushort* __restrict__ Vtmp, ushort* __restrict__ VtG){
  __shared__ ushort tile[32][33];
  int n0 = blockIdx.x * 32, bh = blockIdx.y;
  int b = bh >> 3, h = bh & 7;
  int tx = threadIdx.x & 31, ty = threadIdx.x >> 5;
  for (int i = ty; i < 32; i += 8)
    tile[i][tx] = Vtmp[(size_t)(b*Nn + n0 + i)*Dd + h*DHh + tx];
  __syncthreads();
  for (int i = ty; i < 32; i += 8)
    VtG[(size_t)bh*DHh*Nn + (size_t)i*Nn + n0 + tx] = tile[tx][i];
}

// ---------------- GraphConv gather + residual + LN1 (single-pass stats) -----
__global__ __launch_bounds__(256) void gather_ln_kernel(
    const ushort* __restrict__ xtb, const int* __restrict__ bucketR,
    const float* __restrict__ bucketN, const int* __restrict__ start,
    const float* __restrict__ x, const float* __restrict__ gc_b,
    const float* __restrict__ gamma, const float* __restrict__ beta,
    float* __restrict__ out, ushort* __restrict__ outb){
  int v = blockIdx.x, t = threadIdx.x;
  int s0 = start[v], s1 = start[v+1];
  float acc = 0.f;
  int ii = s0;
  for (; ii + 1 < s1; ii += 2){
    int   r0 = bucketR[ii],   r1 = bucketR[ii+1];
    float n0 = bucketN[ii],   n1 = bucketN[ii+1];
    float v0 = bf2f(xtb[(size_t)r0*Dd + t]);
    float v1 = bf2f(xtb[(size_t)r1*Dd + t]);
    acc += n0 * v0;
    acc += n1 * v1;
  }
  if (ii < s1){
    acc += bucketN[ii] * bf2f(xtb[(size_t)bucketR[ii]*Dd + t]);
  }
  float val = x[(size_t)v*Dd + t] + acc + gc_b[t];

  float s = val, s2 = val*val;
  #pragma unroll
  for (int o = 32; o > 0; o >>= 1){ s += __shfl_xor(s, o); s2 += __shfl_xor(s2, o); }
  __shared__ float wsA[4], wsB[4];
  int wid = t >> 6, lane = t & 63;
  if (lane == 0){ wsA[wid] = s; wsB[wid] = s2; }
  __syncthreads();
  float mu = (wsA[0]+wsA[1]+wsA[2]+wsA[3]) * (1.0f/Dd);
  float ms = (wsB[0]+wsB[1]+wsB[2]+wsB[3]) * (1.0f/Dd);
  float var = ms - mu*mu;
  float res = (val - mu) * rsqrtf(var + 1e-5f) * gamma[t] + beta[t];
  out[(size_t)v*Dd + t] = res;
  outb[(size_t)v*Dd + t] = f2bf(res);
}

__global__ __launch_bounds__(256) void add_ln_kernel(
    const float* __restrict__ a, const float* __restrict__ b,
    const float* __restrict__ gamma, const float* __restrict__ beta,
    float* __restrict__ out, ushort* __restrict__ outb){
  int row = blockIdx.x, t = threadIdx.x;
  size_t off = (size_t)row*Dd + t;
  float val = a[off] + b[off];

  float s = val, s2 = val*val;
  #pragma unroll
  for (int o = 32; o > 0; o >>= 1){ s += __shfl_xor(s, o); s2 += __shfl_xor(s2, o); }
  __shared__ float wsA[4], wsB[4];
  int wid = t >> 6, lane = t & 63;
  if (lane == 0){ wsA[wid] = s; wsB[wid] = s2; }
  __syncthreads();
  float mu = (wsA[0]+wsA[1]+wsA[2]+wsA[3]) * (1.0f/Dd);
  float ms = (wsB[0]+wsB[1]+wsB[2]+wsB[3]) * (1.0f/Dd);
  float var = ms - mu*mu;
  float res = (val - mu) * rsqrtf(var + 1e-5f) * gamma[t] + beta[t];
  out[off] = res;
  if (outb) outb[off] = f2bf(res);
}

// ---------------- bf16 MFMA GEMM, 128x64 tile ----------------
// EPI: 0 = fp32 out, 2 = bf16+gelu out, 3 = QKV routing (Qp/Kp/Vtmp)
#define LDA_S 56

template<int EPI>
__global__ __launch_bounds__(256,2) void gemm_bf16(
    const ushort* __restrict__ A, const ushort* __restrict__ Bt,
    const float* __restrict__ bias, float* __restrict__ Cf, ushort* __restrict__ Cb,
    int M, int K, int N, float qscale,
    ushort* __restrict__ Qp, ushort* __restrict__ Kp, ushort* __restrict__ Vtmp){
  __shared__ ushort As[2][128*LDA_S];
  __shared__ ushort Bs[2][64*LDA_S];
  int t = threadIdx.x;
  int lane = t & 63, wid = t >> 6;
  int wm = wid >> 1, wn = wid & 1;
  int l15 = lane & 15, lg = lane >> 4;
  int m0 = blockIdx.y * 128, n0 = blockIdx.x * 64;

  int sr = t >> 2;
  int sk = (t & 3) * 8;
  const ushort* Ag1 = A  + (size_t)(m0 + sr) * K + sk;
  const ushort* Ag2 = A  + (size_t)(m0 + 64 + sr) * K + sk;
  const ushort* Bg  = Bt + (size_t)(n0 + sr) * K + sk;

  int nsteps = K / 32;
  bf8 ra1 = *(const bf8*)Ag1;
  bf8 ra2 = *(const bf8*)Ag2;
  bf8 rb  = *(const bf8*)Bg;
  *(bf8*)&As[0][sr*LDA_S + sk]        = ra1;
  *(bf8*)&As[0][(64+sr)*LDA_S + sk]   = ra2;
  *(bf8*)&Bs[0][sr*LDA_S + sk]        = rb;
  __syncthreads();

  f4 acc[4][2] = {};
  for (int ks = 0; ks < nsteps; ks++){
    int cur = ks & 1;
    if (ks + 1 < nsteps){
      ra1 = *(const bf8*)(Ag1 + (ks+1)*32);
      ra2 = *(const bf8*)(Ag2 + (ks+1)*32);
      rb  = *(const bf8*)(Bg  + (ks+1)*32);
    }
    bf8 af[4], bfr[2];
    #pragma unroll
    for (int mf = 0; mf < 4; mf++)
      af[mf] = *(bf8*)&As[cur][(wm*64 + mf*16 + l15)*LDA_S + lg*8];
    #pragma unroll
    for (int nf = 0; nf < 2; nf++)
      bfr[nf] = *(bf8*)&Bs[cur][(wn*32 + nf*16 + l15)*LDA_S + lg*8];
    #pragma unroll
    for (int mf = 0; mf < 4; mf++)
      #pragma unroll
      for (int nf = 0; nf < 2; nf++)
        acc[mf][nf] = __builtin_amdgcn_mfma_f32_16x16x32_bf16(af[mf], bfr[nf], acc[mf][nf], 0, 0, 0);
    __syncthreads();
    if (ks + 1 < nsteps){
      int nxt = cur ^ 1;
      *(bf8*)&As[nxt][sr*LDA_S + sk]      = ra1;
      *(bf8*)&As[nxt][(64+sr)*LDA_S + sk] = ra2;
      *(bf8*)&Bs[nxt][sr*LDA_S + sk]      = rb;
      __syncthreads();
    }
  }

  #pragma unroll
  for (int mf = 0; mf < 4; mf++){
    int row = m0 + wm*64 + mf*16 + lg*4;
    #pragma unroll
    for (int nf = 0; nf < 2; nf++){
      int col = n0 + wn*32 + nf*16 + l15;
      float bv = bias ? bias[col] : 0.f;
      #pragma unroll
      for (int r = 0; r < 4; r++){
        int rr = row + r;
        float v = acc[mf][nf][r] + bv;
        if (EPI == 0){
          Cf[(size_t)rr * N + col] = v;
        } else if (EPI == 2){
          Cb[(size_t)rr * N + col] = f2bf(gelu_f(v));
        } else {  // QKV routing
          if (col < 256){
            Qp[(size_t)rr * Dd + col] = f2bf(v * qscale);
          } else if (col < 512){
            int h = (col - 256) >> 5, dh = (col - 256) & 31;
            int bb = rr >> 11, n = rr & 2047;
            Kp[((size_t)(bb*Hh + h)*Nn + n)*DHh + dh] = f2bf(v);
          } else {
            Vtmp[(size_t)rr * Dd + (col - 512)] = f2bf(v);
          }
        }
      }
    }
  }
}

// ---------------- bf16 MFMA GEMM, 64x64 tile (N=256 outputs) --------
template<int OB>
__global__ __launch_bounds__(256,4) void gemm64_bf16(
    const ushort* __restrict__ A, const ushort* __restrict__ Bt,
    const float* __restrict__ bias, float* __restrict__ Cf, ushort* __restrict__ Cb,
    int M, int K, int N){
  __shared__ ushort As[2][64*LDA_S];
  __shared__ ushort Bs[2][64*LDA_S];
  int t = threadIdx.x;
  int lane = t & 63, wid = t >> 6;
  int wm = wid >> 1, wn = wid & 1;
  int l15 = lane & 15, lg = lane >> 4;
  int m0 = blockIdx.y * 64, n0 = blockIdx.x * 64;
  int sr = t >> 2, sk = (t & 3) * 8;
  const ushort* Ag = A  + (size_t)(m0 + sr) * K + sk;
  const ushort* Bg = Bt + (size_t)(n0 + sr) * K + sk;
  int nsteps = K / 32;
  bf8 ra = *(const bf8*)Ag;
  bf8 rb = *(const bf8*)Bg;
  *(bf8*)&As[0][sr*LDA_S + sk] = ra;
  *(bf8*)&Bs[0][sr*LDA_S + sk] = rb;
  __syncthreads();
  f4 acc[2][2] = {};
  for (int ks = 0; ks < nsteps; ks++){
    int cur = ks & 1;
    if (ks + 1 < nsteps){
      ra = *(const bf8*)(Ag + (ks+1)*32);
      rb = *(const bf8*)(Bg + (ks+1)*32);
    }
    bf8 af[2], bfr[2];
    #pragma unroll
    for (int mf = 0; mf < 2; mf++)
      af[mf] = *(bf8*)&As[cur][(wm*32 + mf*16 + l15)*LDA_S + lg*8];
    #pragma unroll
    for (int nf = 0; nf < 2; nf++)
      bfr[nf] = *(bf8*)&Bs[cur][(wn*32 + nf*16 + l15)*LDA_S + lg*8];
    #pragma unroll
    for (int mf = 0; mf < 2; mf++)
      #pragma unroll
      for (int nf = 0; nf < 2; nf++)
        acc[mf][nf] = __builtin_amdgcn_mfma_f32_16x16x32_bf16(af[mf], bfr[nf], acc[mf][nf], 0, 0, 0);
    __syncthreads();
    if (ks + 1 < nsteps){
      int nxt = cur ^ 1;
      *(bf8*)&As[nxt][sr*LDA_S + sk] = ra;
      *(bf8*)&Bs[nxt][sr*LDA_S + sk] = rb;
      __syncthreads();
    }
  }
  #pragma unroll
  for (int mf = 0; mf < 2; mf++){
    int row = m0 + wm*32 + mf*16 + lg*4;
    #pragma unroll
    for (int nf = 0; nf < 2; nf++){
      int col = n0 + wn*32 + nf*16 + l15;
      float bv = bias ? bias[col] : 0.f;
      #pragma unroll
      for (int r = 0; r < 4; r++){
        float v = acc[mf][nf][r] + bv;
        if (OB) Cb[(size_t)(row + r) * N + col] = f2bf(v);
        else    Cf[(size_t)(row + r) * N + col] = v;
      }
    }
  }
}

// ---------------- MFMA flash attention v4 ----------------
// block = (b,h, 128 q rows); 4 waves x 32 q. K,V double-buffered in LDS
// (shared by all 4 waves), 1 barrier/chunk, T14 prefetch. Lane-local exp2
// softmax with defer-max; l reduced once in epilogue.
__global__ __launch_bounds__(256,2) void attn4_kernel(
    const ushort* __restrict__ Qp, const ushort* __restrict__ Kp,
    const ushort* __restrict__ VtG, ushort* __restrict__ AO){
  __shared__ ushort Ks[2][64*KS_S];
  __shared__ ushort Vt[2][32*VT_S];
  __shared__ ushort Pl[4][32*PS];
  int bh = blockIdx.x >> 4, qb = blockIdx.x & 15;
  int b = bh >> 3, h = bh & 7;
  const ushort* Kh = Kp  + (size_t)bh*Nn*DHh;
  const ushort* Vh = VtG + (size_t)bh*DHh*Nn;
  int t = threadIdx.x;
  int lane = t & 63, wid = t >> 6;
  int l15 = lane & 15, lg = lane >> 4;
  int q0 = qb*128 + wid*32;

  // Q B-frags (2 x 16 q)
  bf8 qf[2];
  #pragma unroll
  for (int mf = 0; mf < 2; mf++)
    qf[mf] = *(const bf8*)&Qp[(size_t)(b*Nn + q0 + mf*16 + l15)*Dd + h*DHh + lg*8];

  // staging maps
  int krow = t >> 2, kc8 = (t & 3) * 8;
  int vrow = t >> 3, vc8 = (t & 7) * 8;
  const ushort* Kg = Kh + (size_t)krow*DHh + kc8;
  const ushort* Vg = Vh + (size_t)vrow*Nn + vc8;

  // prologue: stage chunk 0
  bf8 kreg = *(const bf8*)Kg;
  bf8 vreg = *(const bf8*)Vg;
  *(bf8*)&Ks[0][krow*KS_S + kc8] = kreg;
  *(bf8*)&Vt[0][vrow*VT_S + vc8] = vreg;
  __syncthreads();

  float m_st[2] = {-1e30f, -1e30f};
  float l_st[2] = {0.f, 0.f};
  f4 oacc[2][2] = {};
  ushort* Pw = Pl[wid];

  const int NT = Nn/64;
  for (int kc = 0; kc < NT; kc++){
    int cur = kc & 1;
    if (kc + 1 < NT){   // T14: issue early, consumed after compute
      kreg = *(const bf8*)(Kg + (size_t)(kc+1)*64*DHh);
      vreg = *(const bf8*)(Vg + (kc+1)*64);
    }

    // QK^T swapped: D[key][q]; lane: q=l15, keys kt*16+lg*4+r
    f4 s[4][2] = {};
    #pragma unroll
    for (int kt = 0; kt < 4; kt++){
      bf8 kf = *(bf8*)&Ks[cur][(kt*16 + l15)*KS_S + lg*8];
      #pragma unroll
      for (int mf = 0; mf < 2; mf++)
        s[kt][mf] = __builtin_amdgcn_mfma_f32_16x16x32_bf16(kf, qf[mf], s[kt][mf], 0, 0, 0);
    }

    // softmax (exp2 domain; Q pre-scaled by log2e/sqrt(dh))
    #pragma unroll
    for (int mf = 0; mf < 2; mf++){
      float mx = s[0][mf][0];
      #pragma unroll
      for (int kt = 0; kt < 4; kt++)
        #pragma unroll
        for (int r = 0; r < 4; r++)
          mx = fmaxf(mx, s[kt][mf][r]);
      if (__any(mx > m_st[mf] + 11.0f)){
        float mw = fmaxf(mx, __shfl_xor(mx, 16));
        mw = fmaxf(mw, __shfl_xor(mw, 32));
        float Mn = fmaxf(m_st[mf], mw);
        float corr = exp2f(m_st[mf] - Mn);
        l_st[mf] *= corr;
        #pragma unroll
        for (int r = 0; r < 4; r++){
          float cr = __shfl(corr, (lane & 48) | (lg*4 + r));
          oacc[mf][0][r] *= cr;
          oacc[mf][1][r] *= cr;
        }
        m_st[mf] = Mn;
      }
      #pragma unroll
      for (int kt = 0; kt < 4; kt++){
        ushort4 pk;
        ushort* pp = (ushort*)&pk;
        #pragma unroll
        for (int r = 0; r < 4; r++){
          float p = exp2f(s[kt][mf][r] - m_st[mf]);
          unsigned pb = __float_as_uint(p) & 0xffff0000u;  // trunc (p>=0)
          pp[r] = (ushort)(pb >> 16);
          l_st[mf] += __uint_as_float(pb);                  // consistent with PV
        }
        *(ushort4*)&Pw[(mf*16 + l15)*PS + kt*16 + lg*4] = pk;
      }
    }

    // PV: O[32q x 32dh] += P[32x64] V^T  (P wave-private, no barrier)
    #pragma unroll
    for (int mf = 0; mf < 2; mf++)
      #pragma unroll
      for (int ksb = 0; ksb < 2; ksb++){
        bf8 pf = *(bf8*)&Pw[(mf*16 + l15)*PS + ksb*32 + lg*8];
        #pragma unroll
        for (int nt = 0; nt < 2; nt++){
          bf8 vf = *(bf8*)&Vt[cur][(nt*16 + l15)*VT_S + ksb*32 + lg*8];
          oacc[mf][nt] = __builtin_amdgcn_mfma_f32_16x16x32_bf16(pf, vf, oacc[mf][nt], 0, 0, 0);
        }
      }

    // write-late stage of chunk kc+1
    if (kc + 1 < NT){
      *(bf8*)&Ks[cur^1][krow*KS_S + kc8] = kreg;
      *(bf8*)&Vt[cur^1][vrow*VT_S + vc8] = vreg;
    }
    __syncthreads();
  }

  #pragma unroll
  for (int mf = 0; mf < 2; mf++){
    float l = l_st[mf];
    l += __shfl_xor(l, 16);
    l += __shfl_xor(l, 32);
    float invl = 1.0f / l;
    #pragma unroll
    for (int r = 0; r < 4; r++){
      float il = __shfl(invl, (lane & 48) | (lg*4 + r));
      int row = b*Nn + q0 + mf*16 + lg*4 + r;
      #pragma unroll
      for (int nt = 0; nt < 2; nt++)
        AO[(size_t)row*Dd + h*DHh + nt*16 + l15] = f2bf(oacc[mf][nt][r] * il);
    }
  }
}

extern "C" void kernel_launch(void* const* d_in, const int* in_sizes, int n_in,
                              void* d_out, int out_size, void* d_ws, size_t ws_size,
                              hipStream_t stream){
  const float* x      = (const float*)d_in[0];
  const int*   ei     = (const int*)d_in[1];
  const float* gc_w   = (const float*)d_in[2];
  const float* gc_b   = (const float*)d_in[3];
  const float* g_gamma= (const float*)d_in[4];
  const float* g_beta = (const float*)d_in[5];
  const float* wq = (const float*)d_in[6];  const float* bq = (const float*)d_in[7];
  const float* wk = (const float*)d_in[8];  const float* bk = (const float*)d_in[9];
  const float* wv = (const float*)d_in[10]; const float* bv = (const float*)d_in[11];
  const float* wo = (const float*)d_in[12]; const float* bo = (const float*)d_in[13];
  const float* a_gamma = (const float*)d_in[14]; const float* a_beta = (const float*)d_in[15];
  const float* w1 = (const float*)d_in[16]; const float* b1 = (const float*)d_in[17];
  const float* w2 = (const float*)d_in[18]; const float* b2 = (const float*)d_in[19];
  const float* m_gamma = (const float*)d_in[20]; const float* m_beta = (const float*)d_in[21];
  float* out = (float*)d_out;

  const size_t S = (size_t)BNr * Dd;   // 2,097,152

  char* p = (char*)d_ws;
  auto alloc = [&](size_t bytes){ char* r = p; p += (bytes + 255) & ~(size_t)255; return r; };

  float* X1    = (float*)alloc(S * 4);
  float* X2    = (float*)alloc(S * 4);
  float* MO    = (float*)alloc(S * 4);
  float* PROJ  = (float*)alloc(S * 4);
  ushort* Qp   = (ushort*)alloc(S * 2);
  ushort* Kp   = (ushort*)alloc(S * 2);
  ushort* Vtmp = (ushort*)alloc(S * 2);
  ushort* VtG  = (ushort*)alloc(S * 2);
  ushort* regA = (ushort*)alloc(S * 2);   // xbf then AOb
  ushort* regB = (ushort*)alloc(S * 2);   // XTb then X2b
  ushort* X1b  = (ushort*)alloc(S * 2);
  ushort* Hb   = (ushort*)alloc((size_t)BNr * MLPH * 2);
  ushort* gcwT = (ushort*)alloc(65536 * 2);
  ushort* wqkvT= (ushort*)alloc(196608 * 2);
  ushort* woT  = (ushort*)alloc(65536 * 2);
  ushort* w1T  = (ushort*)alloc(262144 * 2);
  ushort* w2T  = (ushort*)alloc(262144 * 2);
  float* bqkv  = (float*)alloc(768 * 4);
  int* cnt_row = (int*)alloc(8192 * 4);
  int* cnt_col = (int*)alloc(8192 * 4);
  int* startA  = (int*)alloc(8200 * 4);
  int* cursor  = (int*)alloc(8192 * 4);
  int* bucketR = (int*)alloc(Ee * 4);
  float* bucketN = (float*)alloc(Ee * 4);
  float* dis   = (float*)alloc(8192 * 4);
  int* flag    = (int*)alloc(256);

  ushort* xbf = regA;  ushort* AOb = regA;
  ushort* XTb = regB;  ushort* X2b = regB;

  hipMemsetAsync(cnt_row, 0, 8192 * sizeof(int), stream);
  hipMemsetAsync(cnt_col, 0, 8192 * sizeof(int), stream);

  // graph prep
  detect_kernel<<<1, 256, 0, stream>>>(ei, flag);
  count_kernel<<<Ee/256, 256, 0, stream>>>(ei, flag, cnt_row, cnt_col);
  scan_kernel<<<1, 256, 0, stream>>>(cnt_col, cnt_row, startA, cursor, dis);
  fill_kernel<<<Ee/256, 256, 0, stream>>>(ei, flag, dis, cursor, bucketR, bucketN);

  // converts
  conv_kernel<<<(int)(S/4/256), 256, 0, stream>>>(x, xbf, (int)(S/4));
  tconv5_kernel<<<dim3(8,8,5), 256, 0, stream>>>(gc_w, wq, wk, wv, wo,
      gcwT, wqkvT, wqkvT + 65536, wqkvT + 131072, woT);
  tconv_kernel<<<dim3(32,8), 256, 0, stream>>>(w1, w1T, 256, 1024);
  tconv_kernel<<<dim3(8,32), 256, 0, stream>>>(w2, w2T, 1024, 256);
  bias_cat_kernel<<<3, 256, 0, stream>>>(bq, bk, bv, bqkv);

  const float qscale = 0.17677669529663687f * 1.4426950408889634f;  // log2e/sqrt(32)

  // xt = x @ gc_w (bf16 out)
  gemm64_bf16<1><<<dim3(Dd/64, BNr/64), 256, 0, stream>>>(
      xbf, gcwT, nullptr, nullptr, XTb, BNr, Dd, Dd);
  // GraphConv gather + residual + LN1
  gather_ln_kernel<<<BNr, 256, 0, stream>>>(XTb, bucketR, bucketN, startA,
                                            x, gc_b, g_gamma, g_beta, X1, X1b);
  // fused QKV, routed epilogue (Q pre-scaled into exp2 domain)
  gemm_bf16<3><<<dim3(768/64, BNr/128), 256, 0, stream>>>(
      X1b, wqkvT, bqkv, nullptr, nullptr, BNr, Dd, 768, qscale, Qp, Kp, Vtmp);
  // V transpose
  vt_kernel<<<dim3(Nn/32, Bb*Hh), 256, 0, stream>>>(Vtmp, VtG);
  // attention
  attn4_kernel<<<Bb*Hh*16, 256, 0, stream>>>(Qp, Kp, VtG, AOb);
  // out proj + LN2
  gemm64_bf16<0><<<dim3(Dd/64, BNr/64), 256, 0, stream>>>(
      AOb, woT, bo, PROJ, nullptr, BNr, Dd, Dd);
  add_ln_kernel<<<BNr, 256, 0, stream>>>(X1, PROJ, a_gamma, a_beta, X2, X2b);
  // MLP
  gemm_bf16<2><<<dim3(MLPH/64, BNr/128), 256, 0, stream>>>(
      X2b, w1T, b1, nullptr, Hb, BNr, Dd, MLPH, 1.0f, nullptr, nullptr, nullptr);
  gemm64_bf16<0><<<dim3(Dd/64, BNr/64), 256, 0, stream>>>(
      Hb, w2T, b2, MO, nullptr, BNr, MLPH, Dd);
  add_ln_kernel<<<BNr, 256, 0, stream>>>(X2, MO, m_gamma, m_beta, out, nullptr);
}

// Round 7
// 341.555 us; speedup vs baseline: 1.4464x; 1.0454x over previous
//
#include <hip/hip_runtime.h>
#include <math.h>

#define Bb 4
#define Nn 2048
#define Dd 256
#define Hh 8
#define DHh 32
#define MLPH 1024
#define Ee 262144
#define BNr 8192
#define KS_S 40        // K LDS row stride (ushorts) = 80B
#define VT_S 72        // Vt LDS row stride = 144B

typedef __attribute__((ext_vector_type(8))) short bf8;   // 8 bf16 in 4 VGPRs
typedef __attribute__((ext_vector_type(4))) short s4v;   // 4 bf16 in 2 VGPRs
typedef __attribute__((ext_vector_type(4))) float f4;

__device__ __forceinline__ float gelu_f(float x){
  return 0.5f * x * (1.0f + erff(x * 0.70710678118654752f));
}

__device__ __forceinline__ ushort f2bf(float f){
  union { float f; unsigned u; } v; v.f = f;
  unsigned r = v.u + 0x7fffu + ((v.u >> 16) & 1u);   // RNE
  return (ushort)(r >> 16);
}
__device__ __forceinline__ float bf2f(ushort u){
  return __uint_as_float((unsigned)u << 16);
}

// ---------------- edge-index dtype detection ----------------
__global__ void detect_kernel(const int* __restrict__ ei, int* flag){
  __shared__ int nz;
  if (threadIdx.x == 0) nz = 0;
  __syncthreads();
  int any = 0;
  for (int i = threadIdx.x; i < 2048; i += 256)
    if (ei[2*i + 1] != 0) any = 1;
  if (any) atomicOr(&nz, 1);
  __syncthreads();
  if (threadIdx.x == 0) *flag = nz ? 0 : 1;  // 1 => int64 layout
}

__global__ void count_kernel(const int* __restrict__ ei, const int* __restrict__ flag,
                             int* cnt_row, int* cnt_col){
  int e = blockIdx.x * 256 + threadIdx.x;
  if (e >= Ee) return;
  int m = *flag;
  int r = m ? ei[2*e]          : ei[e];
  int c = m ? ei[2*(Ee + e)]   : ei[Ee + e];
  atomicAdd(&cnt_row[r], 1);
  atomicAdd(&cnt_col[c], 1);
}

// exclusive prefix sum of col-counts + deg^-0.5 of row-counts
__global__ void scan_kernel(const int* __restrict__ cnt, const int* __restrict__ cnt_row,
                            int* start, int* cursor, float* dis){
  __shared__ int part[256];
  int t = threadIdx.x;
  int s = 0;
  for (int i = 0; i < 32; i++) s += cnt[t*32 + i];
  part[t] = s;
  __syncthreads();
  if (t == 0){
    int run = 0;
    for (int i = 0; i < 256; i++){ int tmp = part[i]; part[i] = run; run += tmp; }
    start[BNr] = run;
  }
  __syncthreads();
  int base = part[t];
  for (int i = 0; i < 32; i++){
    start[t*32 + i]  = base;
    cursor[t*32 + i] = base;
    base += cnt[t*32 + i];
  }
  for (int i = t; i < BNr; i += 256){
    int d = cnt_row[i];
    dis[i] = d > 0 ? 1.0f / sqrtf((float)d) : 0.0f;
  }
}

// bucket edges by destination; pack (source row, premultiplied norm)
__global__ void fill_kernel(const int* __restrict__ ei, const int* __restrict__ flag,
                            const float* __restrict__ dis,
                            int* cursor, int2* bucket){
  int e = blockIdx.x * 256 + threadIdx.x;
  if (e >= Ee) return;
  int m = *flag;
  int r = m ? ei[2*e]        : ei[e];
  int c = m ? ei[2*(Ee + e)] : ei[Ee + e];
  int p = atomicAdd(&cursor[c], 1);
  int2 pk;
  pk.x = r;
  pk.y = __float_as_int(dis[r] * dis[c]);
  bucket[p] = pk;
}

// transpose-convert fp32 [R][C] -> bf16 [C][R]
__device__ __forceinline__ void tconv_body(const float* src, ushort* dst, int R, int C){
  __shared__ float tile[32][33];
  int c0 = blockIdx.x * 32, r0 = blockIdx.y * 32;
  int tx = threadIdx.x & 31, ty = threadIdx.x >> 5;
  for (int i = ty; i < 32; i += 8)
    tile[i][tx] = src[(size_t)(r0 + i) * C + c0 + tx];
  __syncthreads();
  for (int i = ty; i < 32; i += 8)
    dst[(size_t)(c0 + i) * R + r0 + tx] = f2bf(tile[tx][i]);
}

__global__ void tconv_kernel(const float* __restrict__ src, ushort* __restrict__ dst, int R, int C){
  tconv_body(src, dst, R, C);
}

__global__ void tconv5_kernel(const float* s0, const float* s1, const float* s2,
                              const float* s3, const float* s4,
                              ushort* d0, ushort* d1, ushort* d2, ushort* d3, ushort* d4){
  const float* s; ushort* d;
  switch (blockIdx.z){
    case 0: s = s0; d = d0; break;
    case 1: s = s1; d = d1; break;
    case 2: s = s2; d = d2; break;
    case 3: s = s3; d = d3; break;
    default: s = s4; d = d4; break;
  }
  tconv_body(s, d, 256, 256);
}

__global__ void bias_cat_kernel(const float* __restrict__ bq, const float* __restrict__ bk,
                                const float* __restrict__ bv, float* __restrict__ o){
  int i = blockIdx.x * 256 + threadIdx.x;
  if (i < 256) o[i] = bq[i];
  else if (i < 512) o[i] = bk[i - 256];
  else if (i < 768) o[i] = bv[i - 512];
}

// ---------------- GraphConv gather + residual + LN1 ----------------
__global__ __launch_bounds__(256) void gather_ln_kernel(
    const ushort* __restrict__ xtb, const int2* __restrict__ bucket,
    const int* __restrict__ start,
    const float* __restrict__ x, const float* __restrict__ gc_b,
    const float* __restrict__ gamma, const float* __restrict__ beta,
    float* __restrict__ out, ushort* __restrict__ outb){
  int v = blockIdx.x, t = threadIdx.x;
  int s0 = start[v], s1 = start[v+1];
  float acc = 0.f;
  int ii = s0;
  for (; ii + 3 < s1; ii += 4){
    int2 e0 = bucket[ii],   e1 = bucket[ii+1];
    int2 e2 = bucket[ii+2], e3 = bucket[ii+3];
    float v0 = bf2f(xtb[(size_t)e0.x*Dd + t]);
    float v1 = bf2f(xtb[(size_t)e1.x*Dd + t]);
    float v2 = bf2f(xtb[(size_t)e2.x*Dd + t]);
    float v3 = bf2f(xtb[(size_t)e3.x*Dd + t]);
    acc += __int_as_float(e0.y) * v0 + __int_as_float(e1.y) * v1;
    acc += __int_as_float(e2.y) * v2 + __int_as_float(e3.y) * v3;
  }
  for (; ii < s1; ii++){
    int2 e = bucket[ii];
    acc += __int_as_float(e.y) * bf2f(xtb[(size_t)e.x*Dd + t]);
  }
  float val = x[(size_t)v*Dd + t] + acc + gc_b[t];

  float s = val, s2 = val*val;
  #pragma unroll
  for (int o = 32; o > 0; o >>= 1){ s += __shfl_xor(s, o); s2 += __shfl_xor(s2, o); }
  __shared__ float wsA[4], wsB[4];
  int wid = t >> 6, lane = t & 63;
  if (lane == 0){ wsA[wid] = s; wsB[wid] = s2; }
  __syncthreads();
  float mu = (wsA[0]+wsA[1]+wsA[2]+wsA[3]) * (1.0f/Dd);
  float ms = (wsB[0]+wsB[1]+wsB[2]+wsB[3]) * (1.0f/Dd);
  float var = ms - mu*mu;
  float res = (val - mu) * rsqrtf(var + 1e-5f) * gamma[t] + beta[t];
  out[(size_t)v*Dd + t] = res;
  outb[(size_t)v*Dd + t] = f2bf(res);
}

__global__ __launch_bounds__(256) void add_ln_kernel(
    const float* __restrict__ a, const float* __restrict__ b,
    const float* __restrict__ gamma, const float* __restrict__ beta,
    float* __restrict__ out, ushort* __restrict__ outb){
  int row = blockIdx.x, t = threadIdx.x;
  size_t off = (size_t)row*Dd + t;
  float val = a[off] + b[off];

  float s = val, s2 = val*val;
  #pragma unroll
  for (int o = 32; o > 0; o >>= 1){ s += __shfl_xor(s, o); s2 += __shfl_xor(s2, o); }
  __shared__ float wsA[4], wsB[4];
  int wid = t >> 6, lane = t & 63;
  if (lane == 0){ wsA[wid] = s; wsB[wid] = s2; }
  __syncthreads();
  float mu = (wsA[0]+wsA[1]+wsA[2]+wsA[3]) * (1.0f/Dd);
  float ms = (wsB[0]+wsB[1]+wsB[2]+wsB[3]) * (1.0f/Dd);
  float var = ms - mu*mu;
  float res = (val - mu) * rsqrtf(var + 1e-5f) * gamma[t] + beta[t];
  out[off] = res;
  if (outb) outb[off] = f2bf(res);
}

// ---------------- bf16 MFMA GEMM, 128x64 tile ----------------
// EPI: 0 = fp32 out, 2 = bf16+gelu out, 3 = QKV routing (Qp/Kp/VtG direct)
#define LDA_S 56

template<int EPI>
__global__ __launch_bounds__(256,2) void gemm_bf16(
    const ushort* __restrict__ A, const ushort* __restrict__ Bt,
    const float* __restrict__ bias, float* __restrict__ Cf, ushort* __restrict__ Cb,
    int M, int K, int N, float qscale,
    ushort* __restrict__ Qp, ushort* __restrict__ Kp, ushort* __restrict__ VtG){
  __shared__ ushort As[2][128*LDA_S];
  __shared__ ushort Bs[2][64*LDA_S];
  int t = threadIdx.x;
  int lane = t & 63, wid = t >> 6;
  int wm = wid >> 1, wn = wid & 1;
  int l15 = lane & 15, lg = lane >> 4;
  int m0 = blockIdx.y * 128, n0 = blockIdx.x * 64;

  int sr = t >> 2;
  int sk = (t & 3) * 8;
  const ushort* Ag1 = A  + (size_t)(m0 + sr) * K + sk;
  const ushort* Ag2 = A  + (size_t)(m0 + 64 + sr) * K + sk;
  const ushort* Bg  = Bt + (size_t)(n0 + sr) * K + sk;

  int nsteps = K / 32;
  bf8 ra1 = *(const bf8*)Ag1;
  bf8 ra2 = *(const bf8*)Ag2;
  bf8 rb  = *(const bf8*)Bg;
  *(bf8*)&As[0][sr*LDA_S + sk]        = ra1;
  *(bf8*)&As[0][(64+sr)*LDA_S + sk]   = ra2;
  *(bf8*)&Bs[0][sr*LDA_S + sk]        = rb;
  __syncthreads();

  f4 acc[4][2] = {};
  for (int ks = 0; ks < nsteps; ks++){
    int cur = ks & 1;
    if (ks + 1 < nsteps){
      ra1 = *(const bf8*)(Ag1 + (ks+1)*32);
      ra2 = *(const bf8*)(Ag2 + (ks+1)*32);
      rb  = *(const bf8*)(Bg  + (ks+1)*32);
    }
    bf8 af[4], bfr[2];
    #pragma unroll
    for (int mf = 0; mf < 4; mf++)
      af[mf] = *(bf8*)&As[cur][(wm*64 + mf*16 + l15)*LDA_S + lg*8];
    #pragma unroll
    for (int nf = 0; nf < 2; nf++)
      bfr[nf] = *(bf8*)&Bs[cur][(wn*32 + nf*16 + l15)*LDA_S + lg*8];
    #pragma unroll
    for (int mf = 0; mf < 4; mf++)
      #pragma unroll
      for (int nf = 0; nf < 2; nf++)
        acc[mf][nf] = __builtin_amdgcn_mfma_f32_16x16x32_bf16(af[mf], bfr[nf], acc[mf][nf], 0, 0, 0);
    __syncthreads();
    if (ks + 1 < nsteps){
      int nxt = cur ^ 1;
      *(bf8*)&As[nxt][sr*LDA_S + sk]      = ra1;
      *(bf8*)&As[nxt][(64+sr)*LDA_S + sk] = ra2;
      *(bf8*)&Bs[nxt][sr*LDA_S + sk]      = rb;
      __syncthreads();
    }
  }

  #pragma unroll
  for (int mf = 0; mf < 4; mf++){
    int row = m0 + wm*64 + mf*16 + lg*4;
    #pragma unroll
    for (int nf = 0; nf < 2; nf++){
      int col = n0 + wn*32 + nf*16 + l15;
      float bv = bias ? bias[col] : 0.f;
      float vv[4];
      #pragma unroll
      for (int r = 0; r < 4; r++) vv[r] = acc[mf][nf][r] + bv;
      if (EPI == 0){
        #pragma unroll
        for (int r = 0; r < 4; r++) Cf[(size_t)(row + r) * N + col] = vv[r];
      } else if (EPI == 2){
        #pragma unroll
        for (int r = 0; r < 4; r++) Cb[(size_t)(row + r) * N + col] = f2bf(gelu_f(vv[r]));
      } else {
        if (n0 < 256){          // Q, pre-scaled
          #pragma unroll
          for (int r = 0; r < 4; r++)
            Qp[(size_t)(row + r) * Dd + col] = f2bf(vv[r] * qscale);
        } else if (n0 < 512){   // K -> Kp[bh][n][dh]
          int h = (col - 256) >> 5, dh = (col - 256) & 31;
          int bb = row >> 11, n = row & 2047;
          #pragma unroll
          for (int r = 0; r < 4; r++)
            Kp[((size_t)(bb*Hh + h)*Nn + n + r)*DHh + dh] = f2bf(vv[r]);
        } else {                // V -> VtG[bh][dh][n], 4 consecutive n
          int h = (col - 512) >> 5, dh = (col - 512) & 31;
          int bb = row >> 11, n = row & 2047;
          ushort4 pk;
          pk.x = f2bf(vv[0]); pk.y = f2bf(vv[1]);
          pk.z = f2bf(vv[2]); pk.w = f2bf(vv[3]);
          *(ushort4*)&VtG[((size_t)(bb*Hh + h)*DHh + dh)*Nn + n] = pk;
        }
      }
    }
  }
}

// ---------------- bf16 MFMA GEMM, 64x64 tile ----------------
// AF: A is fp32 (convert in staging). OB: bf16 output.
template<int OB, int AF>
__global__ __launch_bounds__(256,4) void gemm64_bf16(
    const void* __restrict__ Av, const ushort* __restrict__ Bt,
    const float* __restrict__ bias, float* __restrict__ Cf, ushort* __restrict__ Cb,
    int M, int K, int N){
  __shared__ ushort As[2][64*LDA_S];
  __shared__ ushort Bs[2][64*LDA_S];
  int t = threadIdx.x;
  int lane = t & 63, wid = t >> 6;
  int wm = wid >> 1, wn = wid & 1;
  int l15 = lane & 15, lg = lane >> 4;
  int m0 = blockIdx.y * 64, n0 = blockIdx.x * 64;
  int sr = t >> 2, sk = (t & 3) * 8;
  const ushort* Ag = (const ushort*)Av + (size_t)(m0 + sr) * K + sk;
  const float*  Af = (const float*)Av  + (size_t)(m0 + sr) * K + sk;
  const ushort* Bg = Bt + (size_t)(n0 + sr) * K + sk;
  int nsteps = K / 32;

  bf8 ra; float4 rf0, rf1;
  if (AF){ rf0 = *(const float4*)Af; rf1 = *(const float4*)(Af + 4); }
  else   { ra = *(const bf8*)Ag; }
  bf8 rb = *(const bf8*)Bg;
  if (AF){
    bf8 c;
    c[0]=(short)f2bf(rf0.x); c[1]=(short)f2bf(rf0.y); c[2]=(short)f2bf(rf0.z); c[3]=(short)f2bf(rf0.w);
    c[4]=(short)f2bf(rf1.x); c[5]=(short)f2bf(rf1.y); c[6]=(short)f2bf(rf1.z); c[7]=(short)f2bf(rf1.w);
    *(bf8*)&As[0][sr*LDA_S + sk] = c;
  } else {
    *(bf8*)&As[0][sr*LDA_S + sk] = ra;
  }
  *(bf8*)&Bs[0][sr*LDA_S + sk] = rb;
  __syncthreads();

  f4 acc[2][2] = {};
  for (int ks = 0; ks < nsteps; ks++){
    int cur = ks & 1;
    if (ks + 1 < nsteps){
      if (AF){ rf0 = *(const float4*)(Af + (ks+1)*32); rf1 = *(const float4*)(Af + (ks+1)*32 + 4); }
      else   { ra = *(const bf8*)(Ag + (ks+1)*32); }
      rb = *(const bf8*)(Bg + (ks+1)*32);
    }
    bf8 af[2], bfr[2];
    #pragma unroll
    for (int mf = 0; mf < 2; mf++)
      af[mf] = *(bf8*)&As[cur][(wm*32 + mf*16 + l15)*LDA_S + lg*8];
    #pragma unroll
    for (int nf = 0; nf < 2; nf++)
      bfr[nf] = *(bf8*)&Bs[cur][(wn*32 + nf*16 + l15)*LDA_S + lg*8];
    #pragma unroll
    for (int mf = 0; mf < 2; mf++)
      #pragma unroll
      for (int nf = 0; nf < 2; nf++)
        acc[mf][nf] = __builtin_amdgcn_mfma_f32_16x16x32_bf16(af[mf], bfr[nf], acc[mf][nf], 0, 0, 0);
    __syncthreads();
    if (ks + 1 < nsteps){
      int nxt = cur ^ 1;
      if (AF){
        bf8 c;
        c[0]=(short)f2bf(rf0.x); c[1]=(short)f2bf(rf0.y); c[2]=(short)f2bf(rf0.z); c[3]=(short)f2bf(rf0.w);
        c[4]=(short)f2bf(rf1.x); c[5]=(short)f2bf(rf1.y); c[6]=(short)f2bf(rf1.z); c[7]=(short)f2bf(rf1.w);
        *(bf8*)&As[nxt][sr*LDA_S + sk] = c;
      } else {
        *(bf8*)&As[nxt][sr*LDA_S + sk] = ra;
      }
      *(bf8*)&Bs[nxt][sr*LDA_S + sk] = rb;
      __syncthreads();
    }
  }
  #pragma unroll
  for (int mf = 0; mf < 2; mf++){
    int row = m0 + wm*32 + mf*16 + lg*4;
    #pragma unroll
    for (int nf = 0; nf < 2; nf++){
      int col = n0 + wn*32 + nf*16 + l15;
      float bv = bias ? bias[col] : 0.f;
      #pragma unroll
      for (int r = 0; r < 4; r++){
        float v = acc[mf][nf][r] + bv;
        if (OB) Cb[(size_t)(row + r) * N + col] = f2bf(v);
        else    Cf[(size_t)(row + r) * N + col] = v;
      }
    }
  }
}

// ---------------- MFMA flash attention v5: P-in-register ----------------
// block = (b,h, 64 q); 4 waves x 16 q. K,V double-buffered in LDS, 1 barrier
// per chunk. Lane-local exp2 softmax + defer-max; PV via 16x16x16 MFMA with
// P staying in registers (A-frag layout matches QK^T swapped output).
__global__ __launch_bounds__(256,4) void attn5_kernel(
    const ushort* __restrict__ Qp, const ushort* __restrict__ Kp,
    const ushort* __restrict__ VtG, ushort* __restrict__ AO){
  __shared__ ushort Ks[2][64*KS_S];
  __shared__ ushort Vt[2][32*VT_S];
  int bh = blockIdx.x >> 5, qb = blockIdx.x & 31;
  int b = bh >> 3, h = bh & 7;
  const ushort* Kh = Kp  + (size_t)bh*Nn*DHh;
  const ushort* Vh = VtG + (size_t)bh*DHh*Nn;
  int t = threadIdx.x;
  int lane = t & 63, wid = t >> 6;
  int l15 = lane & 15, lg = lane >> 4;
  int q0 = qb*64 + wid*16;

  bf8 qf = *(const bf8*)&Qp[(size_t)(b*Nn + q0 + l15)*Dd + h*DHh + lg*8];

  int krow = t >> 2, kc8 = (t & 3) * 8;
  int vrow = t >> 3, vc8 = (t & 7) * 8;
  const ushort* Kg = Kh + (size_t)krow*DHh + kc8;
  const ushort* Vg = Vh + (size_t)vrow*Nn + vc8;

  bf8 kreg = *(const bf8*)Kg;
  bf8 vreg = *(const bf8*)Vg;
  *(bf8*)&Ks[0][krow*KS_S + kc8] = kreg;
  *(bf8*)&Vt[0][vrow*VT_S + vc8] = vreg;
  __syncthreads();

  float m_st = -1e30f, l_st = 0.f;
  f4 oacc[2] = {};

  const int NT = Nn/64;
  for (int kc = 0; kc < NT; kc++){
    int cur = kc & 1;
    if (kc + 1 < NT){   // T14: issue early, write after compute
      kreg = *(const bf8*)(Kg + (size_t)(kc+1)*64*DHh);
      vreg = *(const bf8*)(Vg + (kc+1)*64);
    }

    // QK^T swapped: D[key][q]; lane: q=l15, keys kt*16+lg*4+r
    f4 s[4] = {};
    #pragma unroll
    for (int kt = 0; kt < 4; kt++){
      bf8 kf = *(bf8*)&Ks[cur][(kt*16 + l15)*KS_S + lg*8];
      s[kt] = __builtin_amdgcn_mfma_f32_16x16x32_bf16(kf, qf, s[kt], 0, 0, 0);
    }

    float mx = s[0][0];
    #pragma unroll
    for (int kt = 0; kt < 4; kt++)
      #pragma unroll
      for (int r = 0; r < 4; r++)
        mx = fmaxf(mx, s[kt][r]);
    if (__any(mx > m_st + 11.0f)){
      float mw = fmaxf(mx, __shfl_xor(mx, 16));
      mw = fmaxf(mw, __shfl_xor(mw, 32));
      float Mn = fmaxf(m_st, mw);
      float corr = exp2f(m_st - Mn);
      l_st *= corr;
      #pragma unroll
      for (int r = 0; r < 4; r++){
        float cr = __shfl(corr, (lane & 48) | (lg*4 + r));
        oacc[0][r] *= cr;
        oacc[1][r] *= cr;
      }
      m_st = Mn;
    }

    // P = exp2(s - m), truncated to bf16, packed directly as 16x16x16 A-frags
    s4v pa[4];
    float ps = 0.f;
    #pragma unroll
    for (int kt = 0; kt < 4; kt++){
      unsigned pb[4];
      #pragma unroll
      for (int r = 0; r < 4; r++){
        float p = exp2f(s[kt][r] - m_st);
        pb[r] = __float_as_uint(p) & 0xffff0000u;
        ps += __uint_as_float(pb[r]);
      }
      union { unsigned u[2]; s4v v; } cvt;
      cvt.u[0] = (pb[0] >> 16) | pb[1];
      cvt.u[1] = (pb[2] >> 16) | pb[3];
      pa[kt] = cvt.v;
    }
    ps += __shfl_xor(ps, 16);
    ps += __shfl_xor(ps, 32);
    l_st += ps;

    // PV: O[16q x 32dh] += P[16x64] V^T  — P in regs, V from LDS (8B reads)
    #pragma unroll
    for (int kt = 0; kt < 4; kt++)
      #pragma unroll
      for (int nt = 0; nt < 2; nt++){
        s4v vf = *(const s4v*)&Vt[cur][(nt*16 + l15)*VT_S + kt*16 + lg*4];
        oacc[nt] = __builtin_amdgcn_mfma_f32_16x16x16bf16_1k(pa[kt], vf, oacc[nt], 0, 0, 0);
      }

    if (kc + 1 < NT){
      *(bf8*)&Ks[cur^1][krow*KS_S + kc8] = kreg;
      *(bf8*)&Vt[cur^1][vrow*VT_S + vc8] = vreg;
    }
    __syncthreads();
  }

  float l = l_st;
  l += __shfl_xor(l, 16);
  l += __shfl_xor(l, 32);
  float invl = 1.0f / l;
  #pragma unroll
  for (int r = 0; r < 4; r++){
    float il = __shfl(invl, (lane & 48) | (lg*4 + r));
    int row = b*Nn + q0 + lg*4 + r;
    #pragma unroll
    for (int nt = 0; nt < 2; nt++)
      AO[(size_t)row*Dd + h*DHh + nt*16 + l15] = f2bf(oacc[nt][r] * il);
  }
}

extern "C" void kernel_launch(void* const* d_in, const int* in_sizes, int n_in,
                              void* d_out, int out_size, void* d_ws, size_t ws_size,
                              hipStream_t stream){
  const float* x      = (const float*)d_in[0];
  const int*   ei     = (const int*)d_in[1];
  const float* gc_w   = (const float*)d_in[2];
  const float* gc_b   = (const float*)d_in[3];
  const float* g_gamma= (const float*)d_in[4];
  const float* g_beta = (const float*)d_in[5];
  const float* wq = (const float*)d_in[6];  const float* bq = (const float*)d_in[7];
  const float* wk = (const float*)d_in[8];  const float* bk = (const float*)d_in[9];
  const float* wv = (const float*)d_in[10]; const float* bv = (const float*)d_in[11];
  const float* wo = (const float*)d_in[12]; const float* bo = (const float*)d_in[13];
  const float* a_gamma = (const float*)d_in[14]; const float* a_beta = (const float*)d_in[15];
  const float* w1 = (const float*)d_in[16]; const float* b1 = (const float*)d_in[17];
  const float* w2 = (const float*)d_in[18]; const float* b2 = (const float*)d_in[19];
  const float* m_gamma = (const float*)d_in[20]; const float* m_beta = (const float*)d_in[21];
  float* out = (float*)d_out;

  const size_t S = (size_t)BNr * Dd;   // 2,097,152

  char* p = (char*)d_ws;
  auto alloc = [&](size_t bytes){ char* r = p; p += (bytes + 255) & ~(size_t)255; return r; };

  float* X1    = (float*)alloc(S * 4);
  float* X2    = (float*)alloc(S * 4);
  float* MO    = (float*)alloc(S * 4);
  float* PROJ  = (float*)alloc(S * 4);
  ushort* Qp   = (ushort*)alloc(S * 2);
  ushort* Kp   = (ushort*)alloc(S * 2);
  ushort* VtG  = (ushort*)alloc(S * 2);
  ushort* regA = (ushort*)alloc(S * 2);   // AOb
  ushort* XTb  = (ushort*)alloc(S * 2);   // then X2b
  ushort* X1b  = (ushort*)alloc(S * 2);
  ushort* Hb   = (ushort*)alloc((size_t)BNr * MLPH * 2);
  ushort* gcwT = (ushort*)alloc(65536 * 2);
  ushort* wqkvT= (ushort*)alloc(196608 * 2);
  ushort* woT  = (ushort*)alloc(65536 * 2);
  ushort* w1T  = (ushort*)alloc(262144 * 2);
  ushort* w2T  = (ushort*)alloc(262144 * 2);
  float* bqkv  = (float*)alloc(768 * 4);
  int* cnt_row = (int*)alloc(8192 * 4);
  int* cnt_col = (int*)alloc(8192 * 4);
  int* startA  = (int*)alloc(8200 * 4);
  int* cursor  = (int*)alloc(8192 * 4);
  int2* bucket = (int2*)alloc(Ee * 8);
  float* dis   = (float*)alloc(8192 * 4);
  int* flag    = (int*)alloc(256);

  ushort* AOb = regA;
  ushort* X2b = XTb;

  hipMemsetAsync(cnt_row, 0, 2 * 8192 * sizeof(int), stream);  // cnt_row+cnt_col contiguous

  // graph prep
  detect_kernel<<<1, 256, 0, stream>>>(ei, flag);
  count_kernel<<<Ee/256, 256, 0, stream>>>(ei, flag, cnt_row, cnt_col);
  scan_kernel<<<1, 256, 0, stream>>>(cnt_col, cnt_row, startA, cursor, dis);
  fill_kernel<<<Ee/256, 256, 0, stream>>>(ei, flag, dis, cursor, bucket);

  // weight converts
  tconv5_kernel<<<dim3(8,8,5), 256, 0, stream>>>(gc_w, wq, wk, wv, wo,
      gcwT, wqkvT, wqkvT + 65536, wqkvT + 131072, woT);
  tconv_kernel<<<dim3(32,8), 256, 0, stream>>>(w1, w1T, 256, 1024);
  tconv_kernel<<<dim3(8,32), 256, 0, stream>>>(w2, w2T, 1024, 256);
  bias_cat_kernel<<<3, 256, 0, stream>>>(bq, bk, bv, bqkv);

  const float qscale = 0.17677669529663687f * 1.4426950408889634f;  // log2e/sqrt(32)

  // xt = x @ gc_w (fp32 A staged+converted in-kernel, bf16 out)
  gemm64_bf16<1,1><<<dim3(Dd/64, BNr/64), 256, 0, stream>>>(
      x, gcwT, nullptr, nullptr, XTb, BNr, Dd, Dd);
  // GraphConv gather + residual + LN1
  gather_ln_kernel<<<BNr, 256, 0, stream>>>(XTb, bucket, startA,
                                            x, gc_b, g_gamma, g_beta, X1, X1b);
  // fused QKV, routed epilogue (Q pre-scaled; K packed; V transposed direct)
  gemm_bf16<3><<<dim3(768/64, BNr/128), 256, 0, stream>>>(
      X1b, wqkvT, bqkv, nullptr, nullptr, BNr, Dd, 768, qscale, Qp, Kp, VtG);
  // attention
  attn5_kernel<<<Bb*Hh*32, 256, 0, stream>>>(Qp, Kp, VtG, AOb);
  // out proj + LN2
  gemm64_bf16<0,0><<<dim3(Dd/64, BNr/64), 256, 0, stream>>>(
      AOb, woT, bo, PROJ, nullptr, BNr, Dd, Dd);
  add_ln_kernel<<<BNr, 256, 0, stream>>>(X1, PROJ, a_gamma, a_beta, X2, X2b);
  // MLP
  gemm_bf16<2><<<dim3(MLPH/64, BNr/128), 256, 0, stream>>>(
      X2b, w1T, b1, nullptr, Hb, BNr, Dd, MLPH, 1.0f, nullptr, nullptr, nullptr);
  gemm64_bf16<0,0><<<dim3(Dd/64, BNr/64), 256, 0, stream>>>(
      Hb, w2T, b2, MO, nullptr, BNr, MLPH, Dd);
  add_ln_kernel<<<BNr, 256, 0, stream>>>(X2, MO, m_gamma, m_beta, out, nullptr);
}

// Round 8
// 339.948 us; speedup vs baseline: 1.4532x; 1.0047x over previous
//
#include <hip/hip_runtime.h>
#include <math.h>

#define Bb 4
#define Nn 2048
#define Dd 256
#define Hh 8
#define DHh 32
#define MLPH 1024
#define Ee 262144
#define BNr 8192
#define KS2 40         // attn K LDS row stride (ushorts) = 80B
#define VS2 136        // attn Vt LDS row stride = 272B (128 keys + 8 pad)
#define LDB 72         // GEMM LDS row stride for BK=64 (144B)

typedef __attribute__((ext_vector_type(8))) short bf8;   // 8 bf16 in 4 VGPRs
typedef __attribute__((ext_vector_type(4))) short s4v;   // 4 bf16 in 2 VGPRs
typedef __attribute__((ext_vector_type(4))) float f4;

__device__ __forceinline__ float gelu_f(float x){
  return 0.5f * x * (1.0f + erff(x * 0.70710678118654752f));
}

__device__ __forceinline__ ushort f2bf(float f){
  union { float f; unsigned u; } v; v.f = f;
  unsigned r = v.u + 0x7fffu + ((v.u >> 16) & 1u);   // RNE
  return (ushort)(r >> 16);
}
__device__ __forceinline__ float bf2f(ushort u){
  return __uint_as_float((unsigned)u << 16);
}

// ---------------- edge-index dtype detection ----------------
__global__ void detect_kernel(const int* __restrict__ ei, int* flag){
  __shared__ int nz;
  if (threadIdx.x == 0) nz = 0;
  __syncthreads();
  int any = 0;
  for (int i = threadIdx.x; i < 2048; i += 256)
    if (ei[2*i + 1] != 0) any = 1;
  if (any) atomicOr(&nz, 1);
  __syncthreads();
  if (threadIdx.x == 0) *flag = nz ? 0 : 1;  // 1 => int64 layout
}

__global__ void count_kernel(const int* __restrict__ ei, const int* __restrict__ flag,
                             int* cnt_row, int* cnt_col){
  int e = blockIdx.x * 256 + threadIdx.x;
  if (e >= Ee) return;
  int m = *flag;
  int r = m ? ei[2*e]          : ei[e];
  int c = m ? ei[2*(Ee + e)]   : ei[Ee + e];
  atomicAdd(&cnt_row[r], 1);
  atomicAdd(&cnt_col[c], 1);
}

// exclusive prefix sum of col-counts + deg^-0.5 of row-counts
__global__ void scan_kernel(const int* __restrict__ cnt, const int* __restrict__ cnt_row,
                            int* start, int* cursor, float* dis){
  __shared__ int part[256];
  int t = threadIdx.x;
  int s = 0;
  for (int i = 0; i < 32; i++) s += cnt[t*32 + i];
  part[t] = s;
  __syncthreads();
  if (t == 0){
    int run = 0;
    for (int i = 0; i < 256; i++){ int tmp = part[i]; part[i] = run; run += tmp; }
    start[BNr] = run;
  }
  __syncthreads();
  int base = part[t];
  for (int i = 0; i < 32; i++){
    start[t*32 + i]  = base;
    cursor[t*32 + i] = base;
    base += cnt[t*32 + i];
  }
  for (int i = t; i < BNr; i += 256){
    int d = cnt_row[i];
    dis[i] = d > 0 ? 1.0f / sqrtf((float)d) : 0.0f;
  }
}

// bucket edges by destination; pack (source row, premultiplied norm)
__global__ void fill_kernel(const int* __restrict__ ei, const int* __restrict__ flag,
                            const float* __restrict__ dis,
                            int* cursor, int2* bucket){
  int e = blockIdx.x * 256 + threadIdx.x;
  if (e >= Ee) return;
  int m = *flag;
  int r = m ? ei[2*e]        : ei[e];
  int c = m ? ei[2*(Ee + e)] : ei[Ee + e];
  int p = atomicAdd(&cursor[c], 1);
  int2 pk;
  pk.x = r;
  pk.y = __float_as_int(dis[r] * dis[c]);
  bucket[p] = pk;
}

// transpose-convert fp32 [R][C] -> bf16 [C][R]
__device__ __forceinline__ void tconv_body(const float* src, ushort* dst, int R, int C){
  __shared__ float tile[32][33];
  int c0 = blockIdx.x * 32, r0 = blockIdx.y * 32;
  int tx = threadIdx.x & 31, ty = threadIdx.x >> 5;
  for (int i = ty; i < 32; i += 8)
    tile[i][tx] = src[(size_t)(r0 + i) * C + c0 + tx];
  __syncthreads();
  for (int i = ty; i < 32; i += 8)
    dst[(size_t)(c0 + i) * R + r0 + tx] = f2bf(tile[tx][i]);
}

__global__ void tconv_kernel(const float* __restrict__ src, ushort* __restrict__ dst, int R, int C){
  tconv_body(src, dst, R, C);
}

__global__ void tconv5_kernel(const float* s0, const float* s1, const float* s2,
                              const float* s3, const float* s4,
                              ushort* d0, ushort* d1, ushort* d2, ushort* d3, ushort* d4){
  const float* s; ushort* d;
  switch (blockIdx.z){
    case 0: s = s0; d = d0; break;
    case 1: s = s1; d = d1; break;
    case 2: s = s2; d = d2; break;
    case 3: s = s3; d = d3; break;
    default: s = s4; d = d4; break;
  }
  tconv_body(s, d, 256, 256);
}

__global__ void bias_cat_kernel(const float* __restrict__ bq, const float* __restrict__ bk,
                                const float* __restrict__ bv, float* __restrict__ o){
  int i = blockIdx.x * 256 + threadIdx.x;
  if (i < 256) o[i] = bq[i];
  else if (i < 512) o[i] = bk[i - 256];
  else if (i < 768) o[i] = bv[i - 512];
}

// ---------------- GraphConv gather + residual + LN1 ----------------
__global__ __launch_bounds__(256) void gather_ln_kernel(
    const ushort* __restrict__ xtb, const int2* __restrict__ bucket,
    const int* __restrict__ start,
    const float* __restrict__ x, const float* __restrict__ gc_b,
    const float* __restrict__ gamma, const float* __restrict__ beta,
    float* __restrict__ out, ushort* __restrict__ outb){
  int v = blockIdx.x, t = threadIdx.x;
  int s0 = start[v], s1 = start[v+1];
  float acc = 0.f;
  int ii = s0;
  for (; ii + 3 < s1; ii += 4){
    int2 e0 = bucket[ii],   e1 = bucket[ii+1];
    int2 e2 = bucket[ii+2], e3 = bucket[ii+3];
    float v0 = bf2f(xtb[(size_t)e0.x*Dd + t]);
    float v1 = bf2f(xtb[(size_t)e1.x*Dd + t]);
    float v2 = bf2f(xtb[(size_t)e2.x*Dd + t]);
    float v3 = bf2f(xtb[(size_t)e3.x*Dd + t]);
    acc += __int_as_float(e0.y) * v0 + __int_as_float(e1.y) * v1;
    acc += __int_as_float(e2.y) * v2 + __int_as_float(e3.y) * v3;
  }
  for (; ii < s1; ii++){
    int2 e = bucket[ii];
    acc += __int_as_float(e.y) * bf2f(xtb[(size_t)e.x*Dd + t]);
  }
  float val = x[(size_t)v*Dd + t] + acc + gc_b[t];

  float s = val, s2 = val*val;
  #pragma unroll
  for (int o = 32; o > 0; o >>= 1){ s += __shfl_xor(s, o); s2 += __shfl_xor(s2, o); }
  __shared__ float wsA[4], wsB[4];
  int wid = t >> 6, lane = t & 63;
  if (lane == 0){ wsA[wid] = s; wsB[wid] = s2; }
  __syncthreads();
  float mu = (wsA[0]+wsA[1]+wsA[2]+wsA[3]) * (1.0f/Dd);
  float ms = (wsB[0]+wsB[1]+wsB[2]+wsB[3]) * (1.0f/Dd);
  float var = ms - mu*mu;
  float res = (val - mu) * rsqrtf(var + 1e-5f) * gamma[t] + beta[t];
  out[(size_t)v*Dd + t] = res;
  outb[(size_t)v*Dd + t] = f2bf(res);
}

__global__ __launch_bounds__(256) void add_ln_kernel(
    const float* __restrict__ a, const float* __restrict__ b,
    const float* __restrict__ gamma, const float* __restrict__ beta,
    float* __restrict__ out, ushort* __restrict__ outb){
  int row = blockIdx.x, t = threadIdx.x;
  size_t off = (size_t)row*Dd + t;
  float val = a[off] + b[off];

  float s = val, s2 = val*val;
  #pragma unroll
  for (int o = 32; o > 0; o >>= 1){ s += __shfl_xor(s, o); s2 += __shfl_xor(s2, o); }
  __shared__ float wsA[4], wsB[4];
  int wid = t >> 6, lane = t & 63;
  if (lane == 0){ wsA[wid] = s; wsB[wid] = s2; }
  __syncthreads();
  float mu = (wsA[0]+wsA[1]+wsA[2]+wsA[3]) * (1.0f/Dd);
  float ms = (wsB[0]+wsB[1]+wsB[2]+wsB[3]) * (1.0f/Dd);
  float var = ms - mu*mu;
  float res = (val - mu) * rsqrtf(var + 1e-5f) * gamma[t] + beta[t];
  out[off] = res;
  if (outb) outb[off] = f2bf(res);
}

// ---------------- bf16 MFMA GEMM, 128x64 tile, BK=64 ----------------
// EPI: 0 = fp32 out, 2 = bf16+gelu out, 3 = QKV routing (Qp/Kp/VtG direct)
template<int EPI>
__global__ __launch_bounds__(256,2) void gemm_bf16(
    const ushort* __restrict__ A, const ushort* __restrict__ Bt,
    const float* __restrict__ bias, float* __restrict__ Cf, ushort* __restrict__ Cb,
    int M, int K, int N, float qscale,
    ushort* __restrict__ Qp, ushort* __restrict__ Kp, ushort* __restrict__ VtG){
  __shared__ ushort As[2][128*LDB];
  __shared__ ushort Bs[2][64*LDB];
  int t = threadIdx.x;
  int lane = t & 63, wid = t >> 6;
  int wm = wid >> 1, wn = wid & 1;
  int l15 = lane & 15, lg = lane >> 4;
  int m0 = blockIdx.y * 128, n0 = blockIdx.x * 64;

  int ar = t >> 1, ac = (t & 1) * 32;    // A: 128 rows x 64, 32 elems/thread
  int br = t >> 2, bc = (t & 3) * 16;    // B: 64 rows x 64, 16 elems/thread
  const ushort* Ag = A  + (size_t)(m0 + ar) * K + ac;
  const ushort* Bg = Bt + (size_t)(n0 + br) * K + bc;

  int nsteps = K / 64;
  bf8 a0 = *(const bf8*)(Ag + 0),  a1 = *(const bf8*)(Ag + 8);
  bf8 a2 = *(const bf8*)(Ag + 16), a3 = *(const bf8*)(Ag + 24);
  bf8 b0 = *(const bf8*)(Bg + 0),  b1r = *(const bf8*)(Bg + 8);
  *(bf8*)&As[0][ar*LDB + ac + 0]  = a0;
  *(bf8*)&As[0][ar*LDB + ac + 8]  = a1;
  *(bf8*)&As[0][ar*LDB + ac + 16] = a2;
  *(bf8*)&As[0][ar*LDB + ac + 24] = a3;
  *(bf8*)&Bs[0][br*LDB + bc + 0]  = b0;
  *(bf8*)&Bs[0][br*LDB + bc + 8]  = b1r;
  __syncthreads();

  f4 acc[4][2] = {};
  for (int ks = 0; ks < nsteps; ks++){
    int cur = ks & 1;
    if (ks + 1 < nsteps){
      a0 = *(const bf8*)(Ag + (ks+1)*64 + 0);  a1 = *(const bf8*)(Ag + (ks+1)*64 + 8);
      a2 = *(const bf8*)(Ag + (ks+1)*64 + 16); a3 = *(const bf8*)(Ag + (ks+1)*64 + 24);
      b0 = *(const bf8*)(Bg + (ks+1)*64 + 0);  b1r = *(const bf8*)(Bg + (ks+1)*64 + 8);
    }
    #pragma unroll
    for (int kk = 0; kk < 2; kk++){
      bf8 af[4], bfr[2];
      #pragma unroll
      for (int mf = 0; mf < 4; mf++)
        af[mf] = *(bf8*)&As[cur][(wm*64 + mf*16 + l15)*LDB + kk*32 + lg*8];
      #pragma unroll
      for (int nf = 0; nf < 2; nf++)
        bfr[nf] = *(bf8*)&Bs[cur][(wn*32 + nf*16 + l15)*LDB + kk*32 + lg*8];
      #pragma unroll
      for (int mf = 0; mf < 4; mf++)
        #pragma unroll
        for (int nf = 0; nf < 2; nf++)
          acc[mf][nf] = __builtin_amdgcn_mfma_f32_16x16x32_bf16(af[mf], bfr[nf], acc[mf][nf], 0, 0, 0);
    }
    __syncthreads();
    if (ks + 1 < nsteps){
      int nxt = cur ^ 1;
      *(bf8*)&As[nxt][ar*LDB + ac + 0]  = a0;
      *(bf8*)&As[nxt][ar*LDB + ac + 8]  = a1;
      *(bf8*)&As[nxt][ar*LDB + ac + 16] = a2;
      *(bf8*)&As[nxt][ar*LDB + ac + 24] = a3;
      *(bf8*)&Bs[nxt][br*LDB + bc + 0]  = b0;
      *(bf8*)&Bs[nxt][br*LDB + bc + 8]  = b1r;
      __syncthreads();
    }
  }

  #pragma unroll
  for (int mf = 0; mf < 4; mf++){
    int row = m0 + wm*64 + mf*16 + lg*4;
    #pragma unroll
    for (int nf = 0; nf < 2; nf++){
      int col = n0 + wn*32 + nf*16 + l15;
      float bv = bias ? bias[col] : 0.f;
      float vv[4];
      #pragma unroll
      for (int r = 0; r < 4; r++) vv[r] = acc[mf][nf][r] + bv;
      if (EPI == 0){
        #pragma unroll
        for (int r = 0; r < 4; r++) Cf[(size_t)(row + r) * N + col] = vv[r];
      } else if (EPI == 2){
        #pragma unroll
        for (int r = 0; r < 4; r++) Cb[(size_t)(row + r) * N + col] = f2bf(gelu_f(vv[r]));
      } else {
        if (n0 < 256){          // Q, pre-scaled
          #pragma unroll
          for (int r = 0; r < 4; r++)
            Qp[(size_t)(row + r) * Dd + col] = f2bf(vv[r] * qscale);
        } else if (n0 < 512){   // K -> Kp[bh][n][dh]
          int h = (col - 256) >> 5, dh = (col - 256) & 31;
          int bb = row >> 11, n = row & 2047;
          #pragma unroll
          for (int r = 0; r < 4; r++)
            Kp[((size_t)(bb*Hh + h)*Nn + n + r)*DHh + dh] = f2bf(vv[r]);
        } else {                // V -> VtG[bh][dh][n], 4 consecutive n
          int h = (col - 512) >> 5, dh = (col - 512) & 31;
          int bb = row >> 11, n = row & 2047;
          ushort4 pk;
          pk.x = f2bf(vv[0]); pk.y = f2bf(vv[1]);
          pk.z = f2bf(vv[2]); pk.w = f2bf(vv[3]);
          *(ushort4*)&VtG[((size_t)(bb*Hh + h)*DHh + dh)*Nn + n] = pk;
        }
      }
    }
  }
}

// ---------------- bf16 MFMA GEMM, 64x64 tile, BK=64 ----------------
// AF: A is fp32 (convert in staging). OB: bf16 output.
template<int OB, int AF>
__global__ __launch_bounds__(256,4) void gemm64_bf16(
    const void* __restrict__ Av, const ushort* __restrict__ Bt,
    const float* __restrict__ bias, float* __restrict__ Cf, ushort* __restrict__ Cb,
    int M, int K, int N){
  __shared__ ushort As[2][64*LDB];
  __shared__ ushort Bs[2][64*LDB];
  int t = threadIdx.x;
  int lane = t & 63, wid = t >> 6;
  int wm = wid >> 1, wn = wid & 1;
  int l15 = lane & 15, lg = lane >> 4;
  int m0 = blockIdx.y * 64, n0 = blockIdx.x * 64;
  int ar = t >> 2, ac = (t & 3) * 16;    // 64 rows x 64, 16 elems/thread
  const ushort* Ag = (const ushort*)Av + (size_t)(m0 + ar) * K + ac;
  const float*  Af = (const float*)Av  + (size_t)(m0 + ar) * K + ac;
  const ushort* Bg = Bt + (size_t)(n0 + ar) * K + ac;
  int nsteps = K / 64;

  bf8 a0, a1, b0, b1r;
  float4 rf0, rf1, rf2, rf3;
  if (AF){
    rf0 = *(const float4*)(Af + 0);  rf1 = *(const float4*)(Af + 4);
    rf2 = *(const float4*)(Af + 8);  rf3 = *(const float4*)(Af + 12);
    bf8 c0, c1;
    c0[0]=(short)f2bf(rf0.x); c0[1]=(short)f2bf(rf0.y); c0[2]=(short)f2bf(rf0.z); c0[3]=(short)f2bf(rf0.w);
    c0[4]=(short)f2bf(rf1.x); c0[5]=(short)f2bf(rf1.y); c0[6]=(short)f2bf(rf1.z); c0[7]=(short)f2bf(rf1.w);
    c1[0]=(short)f2bf(rf2.x); c1[1]=(short)f2bf(rf2.y); c1[2]=(short)f2bf(rf2.z); c1[3]=(short)f2bf(rf2.w);
    c1[4]=(short)f2bf(rf3.x); c1[5]=(short)f2bf(rf3.y); c1[6]=(short)f2bf(rf3.z); c1[7]=(short)f2bf(rf3.w);
    a0 = c0; a1 = c1;
  } else {
    a0 = *(const bf8*)(Ag + 0); a1 = *(const bf8*)(Ag + 8);
  }
  b0 = *(const bf8*)(Bg + 0); b1r = *(const bf8*)(Bg + 8);
  *(bf8*)&As[0][ar*LDB + ac + 0] = a0;
  *(bf8*)&As[0][ar*LDB + ac + 8] = a1;
  *(bf8*)&Bs[0][ar*LDB + ac + 0] = b0;
  *(bf8*)&Bs[0][ar*LDB + ac + 8] = b1r;
  __syncthreads();

  f4 acc[2][2] = {};
  for (int ks = 0; ks < nsteps; ks++){
    int cur = ks & 1;
    if (ks + 1 < nsteps){
      if (AF){
        rf0 = *(const float4*)(Af + (ks+1)*64 + 0);  rf1 = *(const float4*)(Af + (ks+1)*64 + 4);
        rf2 = *(const float4*)(Af + (ks+1)*64 + 8);  rf3 = *(const float4*)(Af + (ks+1)*64 + 12);
      } else {
        a0 = *(const bf8*)(Ag + (ks+1)*64 + 0); a1 = *(const bf8*)(Ag + (ks+1)*64 + 8);
      }
      b0 = *(const bf8*)(Bg + (ks+1)*64 + 0); b1r = *(const bf8*)(Bg + (ks+1)*64 + 8);
    }
    #pragma unroll
    for (int kk = 0; kk < 2; kk++){
      bf8 af[2], bfr[2];
      #pragma unroll
      for (int mf = 0; mf < 2; mf++)
        af[mf] = *(bf8*)&As[cur][(wm*32 + mf*16 + l15)*LDB + kk*32 + lg*8];
      #pragma unroll
      for (int nf = 0; nf < 2; nf++)
        bfr[nf] = *(bf8*)&Bs[cur][(wn*32 + nf*16 + l15)*LDB + kk*32 + lg*8];
      #pragma unroll
      for (int mf = 0; mf < 2; mf++)
        #pragma unroll
        for (int nf = 0; nf < 2; nf++)
          acc[mf][nf] = __builtin_amdgcn_mfma_f32_16x16x32_bf16(af[mf], bfr[nf], acc[mf][nf], 0, 0, 0);
    }
    __syncthreads();
    if (ks + 1 < nsteps){
      int nxt = cur ^ 1;
      if (AF){
        bf8 c0, c1;
        c0[0]=(short)f2bf(rf0.x); c0[1]=(short)f2bf(rf0.y); c0[2]=(short)f2bf(rf0.z); c0[3]=(short)f2bf(rf0.w);
        c0[4]=(short)f2bf(rf1.x); c0[5]=(short)f2bf(rf1.y); c0[6]=(short)f2bf(rf1.z); c0[7]=(short)f2bf(rf1.w);
        c1[0]=(short)f2bf(rf2.x); c1[1]=(short)f2bf(rf2.y); c1[2]=(short)f2bf(rf2.z); c1[3]=(short)f2bf(rf2.w);
        c1[4]=(short)f2bf(rf3.x); c1[5]=(short)f2bf(rf3.y); c1[6]=(short)f2bf(rf3.z); c1[7]=(short)f2bf(rf3.w);
        a0 = c0; a1 = c1;
      }
      *(bf8*)&As[nxt][ar*LDB + ac + 0] = a0;
      *(bf8*)&As[nxt][ar*LDB + ac + 8] = a1;
      *(bf8*)&Bs[nxt][ar*LDB + ac + 0] = b0;
      *(bf8*)&Bs[nxt][ar*LDB + ac + 8] = b1r;
      __syncthreads();
    }
  }
  #pragma unroll
  for (int mf = 0; mf < 2; mf++){
    int row = m0 + wm*32 + mf*16 + lg*4;
    #pragma unroll
    for (int nf = 0; nf < 2; nf++){
      int col = n0 + wn*32 + nf*16 + l15;
      float bv = bias ? bias[col] : 0.f;
      #pragma unroll
      for (int r = 0; r < 4; r++){
        float v = acc[mf][nf][r] + bv;
        if (OB) Cb[(size_t)(row + r) * N + col] = f2bf(v);
        else    Cf[(size_t)(row + r) * N + col] = v;
      }
    }
  }
}

// ---------------- MFMA flash attention v6 ----------------
// block = (b,h, 64 q); 4 waves x 16 q; KV chunk = 128 keys, double-buffered
// (16 barriers total). P in registers (16x16x16 PV). Per-lane l partials,
// single epilogue reduce. exp2-domain softmax with defer-max (THR=11).
__global__ __launch_bounds__(256,4) void attn6_kernel(
    const ushort* __restrict__ Qp, const ushort* __restrict__ Kp,
    const ushort* __restrict__ VtG, ushort* __restrict__ AO){
  __shared__ ushort Ks[2][128*KS2];
  __shared__ ushort Vt[2][32*VS2];
  int bh = blockIdx.x >> 5, qb = blockIdx.x & 31;
  int b = bh >> 3, h = bh & 7;
  const ushort* Kh = Kp  + (size_t)bh*Nn*DHh;
  const ushort* Vh = VtG + (size_t)bh*DHh*Nn;
  int t = threadIdx.x;
  int lane = t & 63, wid = t >> 6;
  int l15 = lane & 15, lg = lane >> 4;
  int q0 = qb*64 + wid*16;

  bf8 qf = *(const bf8*)&Qp[(size_t)(b*Nn + q0 + l15)*Dd + h*DHh + lg*8];

  // staging maps: K chunk 128x32 (8KB) -> rows akr, akr+64; V chunk 32x128 (8KB)
  int akr = t >> 2, akc = (t & 3) * 8;
  int avr = t >> 3, avc = (t & 7) * 8;
  const ushort* Kg = Kh + (size_t)akr*DHh + akc;
  const ushort* Vg = Vh + (size_t)avr*Nn + avc;

  bf8 k0r = *(const bf8*)Kg;
  bf8 k1r = *(const bf8*)(Kg + 64*DHh);
  bf8 v0r = *(const bf8*)Vg;
  bf8 v1r = *(const bf8*)(Vg + 64);
  *(bf8*)&Ks[0][akr*KS2 + akc]        = k0r;
  *(bf8*)&Ks[0][(akr + 64)*KS2 + akc] = k1r;
  *(bf8*)&Vt[0][avr*VS2 + avc]        = v0r;
  *(bf8*)&Vt[0][avr*VS2 + avc + 64]   = v1r;
  __syncthreads();

  float m_st = -1e30f, l_st = 0.f;
  f4 oacc[2] = {};

  const int NT = Nn/128;   // 16 chunks
  for (int kc = 0; kc < NT; kc++){
    int cur = kc & 1;
    if (kc + 1 < NT){   // T14: issue early, write after compute
      k0r = *(const bf8*)(Kg + (size_t)(kc+1)*128*DHh);
      k1r = *(const bf8*)(Kg + (size_t)((kc+1)*128 + 64)*DHh);
      v0r = *(const bf8*)(Vg + (kc+1)*128);
      v1r = *(const bf8*)(Vg + (kc+1)*128 + 64);
    }

    // QK^T swapped: D[key][q]; lane: q=l15, keys kt*16+lg*4+r, kt=0..7
    f4 s[8];
    #pragma unroll
    for (int kt = 0; kt < 8; kt++){
      bf8 kf = *(bf8*)&Ks[cur][(kt*16 + l15)*KS2 + lg*8];
      f4 z = {};
      s[kt] = __builtin_amdgcn_mfma_f32_16x16x32_bf16(kf, qf, z, 0, 0, 0);
    }

    // max over the lane's 32 scores (pairwise tree for ILP)
    float mx01 = fmaxf(fmaxf(s[0][0], s[0][1]), fmaxf(s[0][2], s[0][3]));
    float mx23 = fmaxf(fmaxf(s[1][0], s[1][1]), fmaxf(s[1][2], s[1][3]));
    float mx45 = fmaxf(fmaxf(s[2][0], s[2][1]), fmaxf(s[2][2], s[2][3]));
    float mx67 = fmaxf(fmaxf(s[3][0], s[3][1]), fmaxf(s[3][2], s[3][3]));
    #pragma unroll
    for (int kt = 4; kt < 8; kt++){
      float a = fmaxf(fmaxf(s[kt][0], s[kt][1]), fmaxf(s[kt][2], s[kt][3]));
      if (kt == 4) mx01 = fmaxf(mx01, a);
      else if (kt == 5) mx23 = fmaxf(mx23, a);
      else if (kt == 6) mx45 = fmaxf(mx45, a);
      else mx67 = fmaxf(mx67, a);
    }
    float mx = fmaxf(fmaxf(mx01, mx23), fmaxf(mx45, mx67));

    if (__any(mx > m_st + 11.0f)){   // defer-max: ~only first chunk
      float mw = fmaxf(mx, __shfl_xor(mx, 16));
      mw = fmaxf(mw, __shfl_xor(mw, 32));
      float Mn = fmaxf(m_st, mw);
      float corr = exp2f(m_st - Mn);
      l_st *= corr;
      #pragma unroll
      for (int r = 0; r < 4; r++){
        float cr = __shfl(corr, (lane & 48) | (lg*4 + r));
        oacc[0][r] *= cr;
        oacc[1][r] *= cr;
      }
      m_st = Mn;
    }

    // P = exp2(s - m) truncated to bf16, packed as 16x16x16 A-frags; per-lane l
    s4v pa[8];
    float ps = 0.f;
    #pragma unroll
    for (int kt = 0; kt < 8; kt++){
      unsigned pb[4];
      #pragma unroll
      for (int r = 0; r < 4; r++){
        float p = exp2f(s[kt][r] - m_st);
        pb[r] = __float_as_uint(p) & 0xffff0000u;
        ps += __uint_as_float(pb[r]);
      }
      union { unsigned u[2]; s4v v; } cvt;
      cvt.u[0] = (pb[0] >> 16) | pb[1];
      cvt.u[1] = (pb[2] >> 16) | pb[3];
      pa[kt] = cvt.v;
    }
    l_st += ps;   // per-lane partial; reduced once in epilogue

    // PV: O[16q x 32dh] += P[16x128] V^T  — P in regs, V from LDS
    #pragma unroll
    for (int kt = 0; kt < 8; kt++)
      #pragma unroll
      for (int nt = 0; nt < 2; nt++){
        s4v vf = *(const s4v*)&Vt[cur][(nt*16 + l15)*VS2 + kt*16 + lg*4];
        oacc[nt] = __builtin_amdgcn_mfma_f32_16x16x16bf16_1k(pa[kt], vf, oacc[nt], 0, 0, 0);
      }

    if (kc + 1 < NT){
      int nxt = cur ^ 1;
      *(bf8*)&Ks[nxt][akr*KS2 + akc]        = k0r;
      *(bf8*)&Ks[nxt][(akr + 64)*KS2 + akc] = k1r;
      *(bf8*)&Vt[nxt][avr*VS2 + avc]        = v0r;
      *(bf8*)&Vt[nxt][avr*VS2 + avc + 64]   = v1r;
    }
    __syncthreads();
  }

  float l = l_st;
  l += __shfl_xor(l, 16);
  l += __shfl_xor(l, 32);
  float invl = 1.0f / l;
  #pragma unroll
  for (int r = 0; r < 4; r++){
    float il = __shfl(invl, (lane & 48) | (lg*4 + r));
    int row = b*Nn + q0 + lg*4 + r;
    #pragma unroll
    for (int nt = 0; nt < 2; nt++)
      AO[(size_t)row*Dd + h*DHh + nt*16 + l15] = f2bf(oacc[nt][r] * il);
  }
}

extern "C" void kernel_launch(void* const* d_in, const int* in_sizes, int n_in,
                              void* d_out, int out_size, void* d_ws, size_t ws_size,
                              hipStream_t stream){
  const float* x      = (const float*)d_in[0];
  const int*   ei     = (const int*)d_in[1];
  const float* gc_w   = (const float*)d_in[2];
  const float* gc_b   = (const float*)d_in[3];
  const float* g_gamma= (const float*)d_in[4];
  const float* g_beta = (const float*)d_in[5];
  const float* wq = (const float*)d_in[6];  const float* bq = (const float*)d_in[7];
  const float* wk = (const float*)d_in[8];  const float* bk = (const float*)d_in[9];
  const float* wv = (const float*)d_in[10]; const float* bv = (const float*)d_in[11];
  const float* wo = (const float*)d_in[12]; const float* bo = (const float*)d_in[13];
  const float* a_gamma = (const float*)d_in[14]; const float* a_beta = (const float*)d_in[15];
  const float* w1 = (const float*)d_in[16]; const float* b1 = (const float*)d_in[17];
  const float* w2 = (const float*)d_in[18]; const float* b2 = (const float*)d_in[19];
  const float* m_gamma = (const float*)d_in[20]; const float* m_beta = (const float*)d_in[21];
  float* out = (float*)d_out;

  const size_t S = (size_t)BNr * Dd;   // 2,097,152

  char* p = (char*)d_ws;
  auto alloc = [&](size_t bytes){ char* r = p; p += (bytes + 255) & ~(size_t)255; return r; };

  float* X1    = (float*)alloc(S * 4);
  float* X2    = (float*)alloc(S * 4);
  float* MO    = (float*)alloc(S * 4);
  float* PROJ  = (float*)alloc(S * 4);
  ushort* Qp   = (ushort*)alloc(S * 2);
  ushort* Kp   = (ushort*)alloc(S * 2);
  ushort* VtG  = (ushort*)alloc(S * 2);
  ushort* regA = (ushort*)alloc(S * 2);   // AOb
  ushort* XTb  = (ushort*)alloc(S * 2);   // then X2b
  ushort* X1b  = (ushort*)alloc(S * 2);
  ushort* Hb   = (ushort*)alloc((size_t)BNr * MLPH * 2);
  ushort* gcwT = (ushort*)alloc(65536 * 2);
  ushort* wqkvT= (ushort*)alloc(196608 * 2);
  ushort* woT  = (ushort*)alloc(65536 * 2);
  ushort* w1T  = (ushort*)alloc(262144 * 2);
  ushort* w2T  = (ushort*)alloc(262144 * 2);
  float* bqkv  = (float*)alloc(768 * 4);
  int* cnt_row = (int*)alloc(8192 * 4);
  int* cnt_col = (int*)alloc(8192 * 4);
  int* startA  = (int*)alloc(8200 * 4);
  int* cursor  = (int*)alloc(8192 * 4);
  int2* bucket = (int2*)alloc(Ee * 8);
  float* dis   = (float*)alloc(8192 * 4);
  int* flag    = (int*)alloc(256);

  ushort* AOb = regA;
  ushort* X2b = XTb;

  hipMemsetAsync(cnt_row, 0, 2 * 8192 * sizeof(int), stream);  // cnt_row+cnt_col contiguous

  // graph prep
  detect_kernel<<<1, 256, 0, stream>>>(ei, flag);
  count_kernel<<<Ee/256, 256, 0, stream>>>(ei, flag, cnt_row, cnt_col);
  scan_kernel<<<1, 256, 0, stream>>>(cnt_col, cnt_row, startA, cursor, dis);
  fill_kernel<<<Ee/256, 256, 0, stream>>>(ei, flag, dis, cursor, bucket);

  // weight converts
  tconv5_kernel<<<dim3(8,8,5), 256, 0, stream>>>(gc_w, wq, wk, wv, wo,
      gcwT, wqkvT, wqkvT + 65536, wqkvT + 131072, woT);
  tconv_kernel<<<dim3(32,8), 256, 0, stream>>>(w1, w1T, 256, 1024);
  tconv_kernel<<<dim3(8,32), 256, 0, stream>>>(w2, w2T, 1024, 256);
  bias_cat_kernel<<<3, 256, 0, stream>>>(bq, bk, bv, bqkv);

  const float qscale = 0.17677669529663687f * 1.4426950408889634f;  // log2e/sqrt(32)

  // xt = x @ gc_w (fp32 A staged+converted in-kernel, bf16 out)
  gemm64_bf16<1,1><<<dim3(Dd/64, BNr/64), 256, 0, stream>>>(
      x, gcwT, nullptr, nullptr, XTb, BNr, Dd, Dd);
  // GraphConv gather + residual + LN1
  gather_ln_kernel<<<BNr, 256, 0, stream>>>(XTb, bucket, startA,
                                            x, gc_b, g_gamma, g_beta, X1, X1b);
  // fused QKV, routed epilogue (Q pre-scaled; K packed; V transposed direct)
  gemm_bf16<3><<<dim3(768/64, BNr/128), 256, 0, stream>>>(
      X1b, wqkvT, bqkv, nullptr, nullptr, BNr, Dd, 768, qscale, Qp, Kp, VtG);
  // attention
  attn6_kernel<<<Bb*Hh*32, 256, 0, stream>>>(Qp, Kp, VtG, AOb);
  // out proj + LN2
  gemm64_bf16<0,0><<<dim3(Dd/64, BNr/64), 256, 0, stream>>>(
      AOb, woT, bo, PROJ, nullptr, BNr, Dd, Dd);
  add_ln_kernel<<<BNr, 256, 0, stream>>>(X1, PROJ, a_gamma, a_beta, X2, X2b);
  // MLP
  gemm_bf16<2><<<dim3(MLPH/64, BNr/128), 256, 0, stream>>>(
      X2b, w1T, b1, nullptr, Hb, BNr, Dd, MLPH, 1.0f, nullptr, nullptr, nullptr);
  gemm64_bf16<0,0><<<dim3(Dd/64, BNr/64), 256, 0, stream>>>(
      Hb, w2T, b2, MO, nullptr, BNr, MLPH, Dd);
  add_ln_kernel<<<BNr, 256, 0, stream>>>(X2, MO, m_gamma, m_beta, out, nullptr);
}

// Round 9
// 328.211 us; speedup vs baseline: 1.5052x; 1.0358x over previous
//
#include <hip/hip_runtime.h>
#include <math.h>

#define Bb 4
#define Nn 2048
#define Dd 256
#define Hh 8
#define DHh 32
#define MLPH 1024
#define Ee 262144
#define BNr 8192
#define KS2 40         // attn K LDS row stride (ushorts) = 80B
#define VS2 136        // attn Vt LDS row stride = 272B
#define LDB 72         // GEMM LDS row stride for BK=64 (144B)

typedef __attribute__((ext_vector_type(8))) short bf8;   // 8 bf16 in 4 VGPRs
typedef __attribute__((ext_vector_type(4))) short s4v;   // 4 bf16 in 2 VGPRs
typedef __attribute__((ext_vector_type(4))) float f4;

__device__ __forceinline__ float gelu_f(float x){
  return 0.5f * x * (1.0f + erff(x * 0.70710678118654752f));
}

__device__ __forceinline__ ushort f2bf(float f){
  union { float f; unsigned u; } v; v.f = f;
  unsigned r = v.u + 0x7fffu + ((v.u >> 16) & 1u);   // RNE
  return (ushort)(r >> 16);
}
__device__ __forceinline__ float bf2f(ushort u){
  return __uint_as_float((unsigned)u << 16);
}

// ---------------- edge-index dtype detection ----------------
__global__ void detect_kernel(const int* __restrict__ ei, int* flag){
  __shared__ int nz;
  if (threadIdx.x == 0) nz = 0;
  __syncthreads();
  int any = 0;
  for (int i = threadIdx.x; i < 2048; i += 256)
    if (ei[2*i + 1] != 0) any = 1;
  if (any) atomicOr(&nz, 1);
  __syncthreads();
  if (threadIdx.x == 0) *flag = nz ? 0 : 1;  // 1 => int64 layout
}

__global__ void count_kernel(const int* __restrict__ ei, const int* __restrict__ flag,
                             int* cnt_row, int* cnt_col){
  int e = blockIdx.x * 256 + threadIdx.x;
  if (e >= Ee) return;
  int m = *flag;
  int r = m ? ei[2*e]          : ei[e];
  int c = m ? ei[2*(Ee + e)]   : ei[Ee + e];
  atomicAdd(&cnt_row[r], 1);
  atomicAdd(&cnt_col[c], 1);
}

// exclusive prefix sum of col-counts + deg^-0.5 of row-counts
__global__ void scan_kernel(const int* __restrict__ cnt, const int* __restrict__ cnt_row,
                            int* start, int* cursor, float* dis){
  __shared__ int part[256];
  int t = threadIdx.x;
  int s = 0;
  for (int i = 0; i < 32; i++) s += cnt[t*32 + i];
  part[t] = s;
  __syncthreads();
  if (t == 0){
    int run = 0;
    for (int i = 0; i < 256; i++){ int tmp = part[i]; part[i] = run; run += tmp; }
    start[BNr] = run;
  }
  __syncthreads();
  int base = part[t];
  for (int i = 0; i < 32; i++){
    start[t*32 + i]  = base;
    cursor[t*32 + i] = base;
    base += cnt[t*32 + i];
  }
  for (int i = t; i < BNr; i += 256){
    int d = cnt_row[i];
    dis[i] = d > 0 ? 1.0f / sqrtf((float)d) : 0.0f;
  }
}

// bucket edges by destination; pack (source row, premultiplied norm)
__global__ void fill_kernel(const int* __restrict__ ei, const int* __restrict__ flag,
                            const float* __restrict__ dis,
                            int* cursor, int2* bucket){
  int e = blockIdx.x * 256 + threadIdx.x;
  if (e >= Ee) return;
  int m = *flag;
  int r = m ? ei[2*e]        : ei[e];
  int c = m ? ei[2*(Ee + e)] : ei[Ee + e];
  int p = atomicAdd(&cursor[c], 1);
  int2 pk;
  pk.x = r;
  pk.y = __float_as_int(dis[r] * dis[c]);
  bucket[p] = pk;
}

// transpose-convert fp32 [R][C] -> bf16 [C][R]
__device__ __forceinline__ void tconv_body(const float* src, ushort* dst, int R, int C){
  __shared__ float tile[32][33];
  int c0 = blockIdx.x * 32, r0 = blockIdx.y * 32;
  int tx = threadIdx.x & 31, ty = threadIdx.x >> 5;
  for (int i = ty; i < 32; i += 8)
    tile[i][tx] = src[(size_t)(r0 + i) * C + c0 + tx];
  __syncthreads();
  for (int i = ty; i < 32; i += 8)
    dst[(size_t)(c0 + i) * R + r0 + tx] = f2bf(tile[tx][i]);
}

__global__ void tconv_kernel(const float* __restrict__ src, ushort* __restrict__ dst, int R, int C){
  tconv_body(src, dst, R, C);
}

__global__ void tconv5_kernel(const float* s0, const float* s1, const float* s2,
                              const float* s3, const float* s4,
                              ushort* d0, ushort* d1, ushort* d2, ushort* d3, ushort* d4){
  const float* s; ushort* d;
  switch (blockIdx.z){
    case 0: s = s0; d = d0; break;
    case 1: s = s1; d = d1; break;
    case 2: s = s2; d = d2; break;
    case 3: s = s3; d = d3; break;
    default: s = s4; d = d4; break;
  }
  tconv_body(s, d, 256, 256);
}

__global__ void bias_cat_kernel(const float* __restrict__ bq, const float* __restrict__ bk,
                                const float* __restrict__ bv, float* __restrict__ o){
  int i = blockIdx.x * 256 + threadIdx.x;
  if (i < 256) o[i] = bq[i];
  else if (i < 512) o[i] = bk[i - 256];
  else if (i < 768) o[i] = bv[i - 512];
}

// ---------------- GraphConv gather + residual + LN1 (128 thr x 2 cols) -----
__global__ __launch_bounds__(128) void gather_ln_kernel(
    const ushort* __restrict__ xtb, const int2* __restrict__ bucket,
    const int* __restrict__ start,
    const float* __restrict__ x, const float* __restrict__ gc_b,
    const float* __restrict__ gamma, const float* __restrict__ beta,
    float* __restrict__ out, ushort* __restrict__ outb){
  int v = blockIdx.x, t = threadIdx.x;   // cols 2t, 2t+1
  int s0 = start[v], s1 = start[v+1];
  float a0 = 0.f, a1 = 0.f;
  int ii = s0;
  for (; ii + 3 < s1; ii += 4){
    int2 e0 = bucket[ii],   e1 = bucket[ii+1];
    int2 e2 = bucket[ii+2], e3 = bucket[ii+3];
    unsigned w0 = *(const unsigned*)&xtb[(size_t)e0.x*Dd + 2*t];
    unsigned w1 = *(const unsigned*)&xtb[(size_t)e1.x*Dd + 2*t];
    unsigned w2 = *(const unsigned*)&xtb[(size_t)e2.x*Dd + 2*t];
    unsigned w3 = *(const unsigned*)&xtb[(size_t)e3.x*Dd + 2*t];
    float n0 = __int_as_float(e0.y), n1 = __int_as_float(e1.y);
    float n2 = __int_as_float(e2.y), n3 = __int_as_float(e3.y);
    a0 += n0 * __uint_as_float(w0 << 16) + n1 * __uint_as_float(w1 << 16);
    a1 += n0 * __uint_as_float(w0 & 0xffff0000u) + n1 * __uint_as_float(w1 & 0xffff0000u);
    a0 += n2 * __uint_as_float(w2 << 16) + n3 * __uint_as_float(w3 << 16);
    a1 += n2 * __uint_as_float(w2 & 0xffff0000u) + n3 * __uint_as_float(w3 & 0xffff0000u);
  }
  for (; ii < s1; ii++){
    int2 e = bucket[ii];
    unsigned w = *(const unsigned*)&xtb[(size_t)e.x*Dd + 2*t];
    float nn = __int_as_float(e.y);
    a0 += nn * __uint_as_float(w << 16);
    a1 += nn * __uint_as_float(w & 0xffff0000u);
  }
  float2 xv = *(const float2*)&x[(size_t)v*Dd + 2*t];
  float val0 = xv.x + a0 + gc_b[2*t];
  float val1 = xv.y + a1 + gc_b[2*t + 1];

  float s = val0 + val1, s2 = val0*val0 + val1*val1;
  #pragma unroll
  for (int o = 32; o > 0; o >>= 1){ s += __shfl_xor(s, o); s2 += __shfl_xor(s2, o); }
  __shared__ float wsA[2], wsB[2];
  int wid = t >> 6, lane = t & 63;
  if (lane == 0){ wsA[wid] = s; wsB[wid] = s2; }
  __syncthreads();
  float mu = (wsA[0] + wsA[1]) * (1.0f/Dd);
  float ms = (wsB[0] + wsB[1]) * (1.0f/Dd);
  float rstd = rsqrtf(ms - mu*mu + 1e-5f);
  float res0 = (val0 - mu) * rstd * gamma[2*t]   + beta[2*t];
  float res1 = (val1 - mu) * rstd * gamma[2*t+1] + beta[2*t+1];
  *(float2*)&out[(size_t)v*Dd + 2*t] = make_float2(res0, res1);
  unsigned pk = (unsigned)f2bf(res0) | ((unsigned)f2bf(res1) << 16);
  *(unsigned*)&outb[(size_t)v*Dd + 2*t] = pk;
}

__global__ __launch_bounds__(256) void add_ln_kernel(
    const float* __restrict__ a, const float* __restrict__ b,
    const float* __restrict__ gamma, const float* __restrict__ beta,
    float* __restrict__ out, ushort* __restrict__ outb){
  int row = blockIdx.x, t = threadIdx.x;
  size_t off = (size_t)row*Dd + t;
  float val = a[off] + b[off];

  float s = val, s2 = val*val;
  #pragma unroll
  for (int o = 32; o > 0; o >>= 1){ s += __shfl_xor(s, o); s2 += __shfl_xor(s2, o); }
  __shared__ float wsA[4], wsB[4];
  int wid = t >> 6, lane = t & 63;
  if (lane == 0){ wsA[wid] = s; wsB[wid] = s2; }
  __syncthreads();
  float mu = (wsA[0]+wsA[1]+wsA[2]+wsA[3]) * (1.0f/Dd);
  float ms = (wsB[0]+wsB[1]+wsB[2]+wsB[3]) * (1.0f/Dd);
  float var = ms - mu*mu;
  float res = (val - mu) * rsqrtf(var + 1e-5f) * gamma[t] + beta[t];
  out[off] = res;
  if (outb) outb[off] = f2bf(res);
}

// ---------------- bf16 MFMA GEMM, 128x64 tile, BK=64 ----------------
// EPI: 0 = fp32 out, 2 = bf16+gelu out, 3 = QKV routing (Qp/Kp/VtG direct)
template<int EPI>
__global__ __launch_bounds__(256,2) void gemm_bf16(
    const ushort* __restrict__ A, const ushort* __restrict__ Bt,
    const float* __restrict__ bias, float* __restrict__ Cf, ushort* __restrict__ Cb,
    int M, int K, int N, float qscale,
    ushort* __restrict__ Qp, ushort* __restrict__ Kp, ushort* __restrict__ VtG){
  __shared__ ushort As[2][128*LDB];
  __shared__ ushort Bs[2][64*LDB];
  int t = threadIdx.x;
  int lane = t & 63, wid = t >> 6;
  int wm = wid >> 1, wn = wid & 1;
  int l15 = lane & 15, lg = lane >> 4;
  int m0 = blockIdx.y * 128, n0 = blockIdx.x * 64;

  int ar = t >> 1, ac = (t & 1) * 32;    // A: 128 rows x 64, 32 elems/thread
  int br = t >> 2, bc = (t & 3) * 16;    // B: 64 rows x 64, 16 elems/thread
  const ushort* Ag = A  + (size_t)(m0 + ar) * K + ac;
  const ushort* Bg = Bt + (size_t)(n0 + br) * K + bc;

  int nsteps = K / 64;
  bf8 a0 = *(const bf8*)(Ag + 0),  a1 = *(const bf8*)(Ag + 8);
  bf8 a2 = *(const bf8*)(Ag + 16), a3 = *(const bf8*)(Ag + 24);
  bf8 b0 = *(const bf8*)(Bg + 0),  b1r = *(const bf8*)(Bg + 8);
  *(bf8*)&As[0][ar*LDB + ac + 0]  = a0;
  *(bf8*)&As[0][ar*LDB + ac + 8]  = a1;
  *(bf8*)&As[0][ar*LDB + ac + 16] = a2;
  *(bf8*)&As[0][ar*LDB + ac + 24] = a3;
  *(bf8*)&Bs[0][br*LDB + bc + 0]  = b0;
  *(bf8*)&Bs[0][br*LDB + bc + 8]  = b1r;
  __syncthreads();

  f4 acc[4][2] = {};
  for (int ks = 0; ks < nsteps; ks++){
    int cur = ks & 1;
    if (ks + 1 < nsteps){
      a0 = *(const bf8*)(Ag + (ks+1)*64 + 0);  a1 = *(const bf8*)(Ag + (ks+1)*64 + 8);
      a2 = *(const bf8*)(Ag + (ks+1)*64 + 16); a3 = *(const bf8*)(Ag + (ks+1)*64 + 24);
      b0 = *(const bf8*)(Bg + (ks+1)*64 + 0);  b1r = *(const bf8*)(Bg + (ks+1)*64 + 8);
    }
    #pragma unroll
    for (int kk = 0; kk < 2; kk++){
      bf8 af[4], bfr[2];
      #pragma unroll
      for (int mf = 0; mf < 4; mf++)
        af[mf] = *(bf8*)&As[cur][(wm*64 + mf*16 + l15)*LDB + kk*32 + lg*8];
      #pragma unroll
      for (int nf = 0; nf < 2; nf++)
        bfr[nf] = *(bf8*)&Bs[cur][(wn*32 + nf*16 + l15)*LDB + kk*32 + lg*8];
      #pragma unroll
      for (int mf = 0; mf < 4; mf++)
        #pragma unroll
        for (int nf = 0; nf < 2; nf++)
          acc[mf][nf] = __builtin_amdgcn_mfma_f32_16x16x32_bf16(af[mf], bfr[nf], acc[mf][nf], 0, 0, 0);
    }
    __syncthreads();
    if (ks + 1 < nsteps){
      int nxt = cur ^ 1;
      *(bf8*)&As[nxt][ar*LDB + ac + 0]  = a0;
      *(bf8*)&As[nxt][ar*LDB + ac + 8]  = a1;
      *(bf8*)&As[nxt][ar*LDB + ac + 16] = a2;
      *(bf8*)&As[nxt][ar*LDB + ac + 24] = a3;
      *(bf8*)&Bs[nxt][br*LDB + bc + 0]  = b0;
      *(bf8*)&Bs[nxt][br*LDB + bc + 8]  = b1r;
      __syncthreads();
    }
  }

  #pragma unroll
  for (int mf = 0; mf < 4; mf++){
    int row = m0 + wm*64 + mf*16 + lg*4;
    #pragma unroll
    for (int nf = 0; nf < 2; nf++){
      int col = n0 + wn*32 + nf*16 + l15;
      float bv = bias ? bias[col] : 0.f;
      float vv[4];
      #pragma unroll
      for (int r = 0; r < 4; r++) vv[r] = acc[mf][nf][r] + bv;
      if (EPI == 0){
        #pragma unroll
        for (int r = 0; r < 4; r++) Cf[(size_t)(row + r) * N + col] = vv[r];
      } else if (EPI == 2){
        #pragma unroll
        for (int r = 0; r < 4; r++) Cb[(size_t)(row + r) * N + col] = f2bf(gelu_f(vv[r]));
      } else {
        if (n0 < 256){          // Q, pre-scaled
          #pragma unroll
          for (int r = 0; r < 4; r++)
            Qp[(size_t)(row + r) * Dd + col] = f2bf(vv[r] * qscale);
        } else if (n0 < 512){   // K -> Kp[bh][n][dh]
          int h = (col - 256) >> 5, dh = (col - 256) & 31;
          int bb = row >> 11, n = row & 2047;
          #pragma unroll
          for (int r = 0; r < 4; r++)
            Kp[((size_t)(bb*Hh + h)*Nn + n + r)*DHh + dh] = f2bf(vv[r]);
        } else {                // V -> VtG[bh][dh][n], 4 consecutive n
          int h = (col - 512) >> 5, dh = (col - 512) & 31;
          int bb = row >> 11, n = row & 2047;
          ushort4 pk;
          pk.x = f2bf(vv[0]); pk.y = f2bf(vv[1]);
          pk.z = f2bf(vv[2]); pk.w = f2bf(vv[3]);
          *(ushort4*)&VtG[((size_t)(bb*Hh + h)*DHh + dh)*Nn + n] = pk;
        }
      }
    }
  }
}

// ---------------- bf16 MFMA GEMM, 64x64 tile, BK=64 ----------------
// AF: A is fp32 (convert in staging). OB: bf16 output.
template<int OB, int AF>
__global__ __launch_bounds__(256,4) void gemm64_bf16(
    const void* __restrict__ Av, const ushort* __restrict__ Bt,
    const float* __restrict__ bias, float* __restrict__ Cf, ushort* __restrict__ Cb,
    int M, int K, int N){
  __shared__ ushort As[2][64*LDB];
  __shared__ ushort Bs[2][64*LDB];
  int t = threadIdx.x;
  int lane = t & 63, wid = t >> 6;
  int wm = wid >> 1, wn = wid & 1;
  int l15 = lane & 15, lg = lane >> 4;
  int m0 = blockIdx.y * 64, n0 = blockIdx.x * 64;
  int ar = t >> 2, ac = (t & 3) * 16;    // 64 rows x 64, 16 elems/thread
  const ushort* Ag = (const ushort*)Av + (size_t)(m0 + ar) * K + ac;
  const float*  Af = (const float*)Av  + (size_t)(m0 + ar) * K + ac;
  const ushort* Bg = Bt + (size_t)(n0 + ar) * K + ac;
  int nsteps = K / 64;

  bf8 a0, a1, b0, b1r;
  float4 rf0, rf1, rf2, rf3;
  if (AF){
    rf0 = *(const float4*)(Af + 0);  rf1 = *(const float4*)(Af + 4);
    rf2 = *(const float4*)(Af + 8);  rf3 = *(const float4*)(Af + 12);
    bf8 c0, c1;
    c0[0]=(short)f2bf(rf0.x); c0[1]=(short)f2bf(rf0.y); c0[2]=(short)f2bf(rf0.z); c0[3]=(short)f2bf(rf0.w);
    c0[4]=(short)f2bf(rf1.x); c0[5]=(short)f2bf(rf1.y); c0[6]=(short)f2bf(rf1.z); c0[7]=(short)f2bf(rf1.w);
    c1[0]=(short)f2bf(rf2.x); c1[1]=(short)f2bf(rf2.y); c1[2]=(short)f2bf(rf2.z); c1[3]=(short)f2bf(rf2.w);
    c1[4]=(short)f2bf(rf3.x); c1[5]=(short)f2bf(rf3.y); c1[6]=(short)f2bf(rf3.z); c1[7]=(short)f2bf(rf3.w);
    a0 = c0; a1 = c1;
  } else {
    a0 = *(const bf8*)(Ag + 0); a1 = *(const bf8*)(Ag + 8);
  }
  b0 = *(const bf8*)(Bg + 0); b1r = *(const bf8*)(Bg + 8);
  *(bf8*)&As[0][ar*LDB + ac + 0] = a0;
  *(bf8*)&As[0][ar*LDB + ac + 8] = a1;
  *(bf8*)&Bs[0][ar*LDB + ac + 0] = b0;
  *(bf8*)&Bs[0][ar*LDB + ac + 8] = b1r;
  __syncthreads();

  f4 acc[2][2] = {};
  for (int ks = 0; ks < nsteps; ks++){
    int cur = ks & 1;
    if (ks + 1 < nsteps){
      if (AF){
        rf0 = *(const float4*)(Af + (ks+1)*64 + 0);  rf1 = *(const float4*)(Af + (ks+1)*64 + 4);
        rf2 = *(const float4*)(Af + (ks+1)*64 + 8);  rf3 = *(const float4*)(Af + (ks+1)*64 + 12);
      } else {
        a0 = *(const bf8*)(Ag + (ks+1)*64 + 0); a1 = *(const bf8*)(Ag + (ks+1)*64 + 8);
      }
      b0 = *(const bf8*)(Bg + (ks+1)*64 + 0); b1r = *(const bf8*)(Bg + (ks+1)*64 + 8);
    }
    #pragma unroll
    for (int kk = 0; kk < 2; kk++){
      bf8 af[2], bfr[2];
      #pragma unroll
      for (int mf = 0; mf < 2; mf++)
        af[mf] = *(bf8*)&As[cur][(wm*32 + mf*16 + l15)*LDB + kk*32 + lg*8];
      #pragma unroll
      for (int nf = 0; nf < 2; nf++)
        bfr[nf] = *(bf8*)&Bs[cur][(wn*32 + nf*16 + l15)*LDB + kk*32 + lg*8];
      #pragma unroll
      for (int mf = 0; mf < 2; mf++)
        #pragma unroll
        for (int nf = 0; nf < 2; nf++)
          acc[mf][nf] = __builtin_amdgcn_mfma_f32_16x16x32_bf16(af[mf], bfr[nf], acc[mf][nf], 0, 0, 0);
    }
    __syncthreads();
    if (ks + 1 < nsteps){
      int nxt = cur ^ 1;
      if (AF){
        bf8 c0, c1;
        c0[0]=(short)f2bf(rf0.x); c0[1]=(short)f2bf(rf0.y); c0[2]=(short)f2bf(rf0.z); c0[3]=(short)f2bf(rf0.w);
        c0[4]=(short)f2bf(rf1.x); c0[5]=(short)f2bf(rf1.y); c0[6]=(short)f2bf(rf1.z); c0[7]=(short)f2bf(rf1.w);
        c1[0]=(short)f2bf(rf2.x); c1[1]=(short)f2bf(rf2.y); c1[2]=(short)f2bf(rf2.z); c1[3]=(short)f2bf(rf2.w);
        c1[4]=(short)f2bf(rf3.x); c1[5]=(short)f2bf(rf3.y); c1[6]=(short)f2bf(rf3.z); c1[7]=(short)f2bf(rf3.w);
        a0 = c0; a1 = c1;
      }
      *(bf8*)&As[nxt][ar*LDB + ac + 0] = a0;
      *(bf8*)&As[nxt][ar*LDB + ac + 8] = a1;
      *(bf8*)&Bs[nxt][ar*LDB + ac + 0] = b0;
      *(bf8*)&Bs[nxt][ar*LDB + ac + 8] = b1r;
      __syncthreads();
    }
  }
  #pragma unroll
  for (int mf = 0; mf < 2; mf++){
    int row = m0 + wm*32 + mf*16 + lg*4;
    #pragma unroll
    for (int nf = 0; nf < 2; nf++){
      int col = n0 + wn*32 + nf*16 + l15;
      float bv = bias ? bias[col] : 0.f;
      #pragma unroll
      for (int r = 0; r < 4; r++){
        float v = acc[mf][nf][r] + bv;
        if (OB) Cb[(size_t)(row + r) * N + col] = f2bf(v);
        else    Cf[(size_t)(row + r) * N + col] = v;
      }
    }
  }
}

// ---------------- MFMA flash attention v7: l on the MFMA pipe ----------------
// block = (b,h, 64 q); 4 waves x 16 q; KV chunk = 128 keys, double-buffered.
// P in registers; l computed by ones-MFMA (lands in D-layout: no shuffles);
// max3-shaped max tree; exp2-domain softmax with defer-max (THR=11).
__global__ __launch_bounds__(256,4) void attn7_kernel(
    const ushort* __restrict__ Qp, const ushort* __restrict__ Kp,
    const ushort* __restrict__ VtG, ushort* __restrict__ AO){
  __shared__ ushort Ks[2][128*KS2];
  __shared__ ushort Vt[2][32*VS2];
  int bh = blockIdx.x >> 5, qb = blockIdx.x & 31;
  int b = bh >> 3, h = bh & 7;
  const ushort* Kh = Kp  + (size_t)bh*Nn*DHh;
  const ushort* Vh = VtG + (size_t)bh*DHh*Nn;
  int t = threadIdx.x;
  int lane = t & 63, wid = t >> 6;
  int l15 = lane & 15, lg = lane >> 4;
  int q0 = qb*64 + wid*16;

  bf8 qf = *(const bf8*)&Qp[(size_t)(b*Nn + q0 + l15)*Dd + h*DHh + lg*8];

  s4v ones;
  ones[0] = ones[1] = ones[2] = ones[3] = (short)0x3F80;   // bf16 1.0

  int akr = t >> 2, akc = (t & 3) * 8;
  int avr = t >> 3, avc = (t & 7) * 8;
  const ushort* Kg = Kh + (size_t)akr*DHh + akc;
  const ushort* Vg = Vh + (size_t)avr*Nn + avc;

  bf8 k0r = *(const bf8*)Kg;
  bf8 k1r = *(const bf8*)(Kg + 64*DHh);
  bf8 v0r = *(const bf8*)Vg;
  bf8 v1r = *(const bf8*)(Vg + 64);
  *(bf8*)&Ks[0][akr*KS2 + akc]        = k0r;
  *(bf8*)&Ks[0][(akr + 64)*KS2 + akc] = k1r;
  *(bf8*)&Vt[0][avr*VS2 + avc]        = v0r;
  *(bf8*)&Vt[0][avr*VS2 + avc + 64]   = v1r;
  __syncthreads();

  float m_st = -1e30f;
  f4 oacc[2] = {};
  f4 lacc = {};    // row sums of P, D-layout (row q = lg*4+r)

  const int NT = Nn/128;   // 16 chunks
  for (int kc = 0; kc < NT; kc++){
    int cur = kc & 1;
    if (kc + 1 < NT){   // T14: issue early, write after compute
      k0r = *(const bf8*)(Kg + (size_t)(kc+1)*128*DHh);
      k1r = *(const bf8*)(Kg + (size_t)((kc+1)*128 + 64)*DHh);
      v0r = *(const bf8*)(Vg + (kc+1)*128);
      v1r = *(const bf8*)(Vg + (kc+1)*128 + 64);
    }

    // QK^T swapped: D[key][q]; lane: q=l15, keys kt*16+lg*4+r, kt=0..7
    f4 s[8];
    #pragma unroll
    for (int kt = 0; kt < 8; kt++){
      bf8 kf = *(bf8*)&Ks[cur][(kt*16 + l15)*KS2 + lg*8];
      f4 z = {};
      s[kt] = __builtin_amdgcn_mfma_f32_16x16x32_bf16(kf, qf, z, 0, 0, 0);
    }

    // max over 32 scores; 3-ary nesting -> v_max3
    float mk[8];
    #pragma unroll
    for (int kt = 0; kt < 8; kt++)
      mk[kt] = fmaxf(fmaxf(fmaxf(s[kt][0], s[kt][1]), s[kt][2]), s[kt][3]);
    float mA = fmaxf(fmaxf(mk[0], mk[1]), mk[2]);
    float mB = fmaxf(fmaxf(mk[3], mk[4]), mk[5]);
    float mC = fmaxf(mk[6], mk[7]);
    float mx = fmaxf(fmaxf(mA, mB), mC);

    if (__any(mx > m_st + 11.0f)){   // defer-max: ~only first chunk
      float mw = fmaxf(mx, __shfl_xor(mx, 16));
      mw = fmaxf(mw, __shfl_xor(mw, 32));
      float Mn = fmaxf(m_st, mw);
      float corr = exp2f(m_st - Mn);
      #pragma unroll
      for (int r = 0; r < 4; r++){
        float cr = __shfl(corr, (lane & 48) | (lg*4 + r));
        oacc[0][r] *= cr;
        oacc[1][r] *= cr;
        lacc[r] *= cr;
      }
      m_st = Mn;
    }

    // P = exp2(s - m) truncated to bf16, pair-packed as 16x16x16 A-frags
    s4v pa[8];
    #pragma unroll
    for (int kt = 0; kt < 8; kt++){
      float p0 = exp2f(s[kt][0] - m_st);
      float p1 = exp2f(s[kt][1] - m_st);
      float p2 = exp2f(s[kt][2] - m_st);
      float p3 = exp2f(s[kt][3] - m_st);
      union { unsigned u[2]; s4v v; } cvt;
      cvt.u[0] = (__float_as_uint(p1) & 0xffff0000u) | (__float_as_uint(p0) >> 16);
      cvt.u[1] = (__float_as_uint(p3) & 0xffff0000u) | (__float_as_uint(p2) >> 16);
      pa[kt] = cvt.v;
    }

    // PV + l: O += P V^T, l += P·1  (l on the MFMA pipe, D-layout)
    #pragma unroll
    for (int kt = 0; kt < 8; kt++){
      lacc = __builtin_amdgcn_mfma_f32_16x16x16bf16_1k(pa[kt], ones, lacc, 0, 0, 0);
      #pragma unroll
      for (int nt = 0; nt < 2; nt++){
        s4v vf = *(const s4v*)&Vt[cur][(nt*16 + l15)*VS2 + kt*16 + lg*4];
        oacc[nt] = __builtin_amdgcn_mfma_f32_16x16x16bf16_1k(pa[kt], vf, oacc[nt], 0, 0, 0);
      }
    }

    if (kc + 1 < NT){
      int nxt = cur ^ 1;
      *(bf8*)&Ks[nxt][akr*KS2 + akc]        = k0r;
      *(bf8*)&Ks[nxt][(akr + 64)*KS2 + akc] = k1r;
      *(bf8*)&Vt[nxt][avr*VS2 + avc]        = v0r;
      *(bf8*)&Vt[nxt][avr*VS2 + avc + 64]   = v1r;
    }
    __syncthreads();
  }

  // epilogue: lacc already in D-layout -> no cross-lane shuffles
  #pragma unroll
  for (int r = 0; r < 4; r++){
    float il = 1.0f / lacc[r];
    int row = b*Nn + q0 + lg*4 + r;
    #pragma unroll
    for (int nt = 0; nt < 2; nt++)
      AO[(size_t)row*Dd + h*DHh + nt*16 + l15] = f2bf(oacc[nt][r] * il);
  }
}

extern "C" void kernel_launch(void* const* d_in, const int* in_sizes, int n_in,
                              void* d_out, int out_size, void* d_ws, size_t ws_size,
                              hipStream_t stream){
  const float* x      = (const float*)d_in[0];
  const int*   ei     = (const int*)d_in[1];
  const float* gc_w   = (const float*)d_in[2];
  const float* gc_b   = (const float*)d_in[3];
  const float* g_gamma= (const float*)d_in[4];
  const float* g_beta = (const float*)d_in[5];
  const float* wq = (const float*)d_in[6];  const float* bq = (const float*)d_in[7];
  const float* wk = (const float*)d_in[8];  const float* bk = (const float*)d_in[9];
  const float* wv = (const float*)d_in[10]; const float* bv = (const float*)d_in[11];
  const float* wo = (const float*)d_in[12]; const float* bo = (const float*)d_in[13];
  const float* a_gamma = (const float*)d_in[14]; const float* a_beta = (const float*)d_in[15];
  const float* w1 = (const float*)d_in[16]; const float* b1 = (const float*)d_in[17];
  const float* w2 = (const float*)d_in[18]; const float* b2 = (const float*)d_in[19];
  const float* m_gamma = (const float*)d_in[20]; const float* m_beta = (const float*)d_in[21];
  float* out = (float*)d_out;

  const size_t S = (size_t)BNr * Dd;   // 2,097,152

  char* p = (char*)d_ws;
  auto alloc = [&](size_t bytes){ char* r = p; p += (bytes + 255) & ~(size_t)255; return r; };

  float* X1    = (float*)alloc(S * 4);
  float* X2    = (float*)alloc(S * 4);
  float* MO    = (float*)alloc(S * 4);
  float* PROJ  = (float*)alloc(S * 4);
  ushort* Qp   = (ushort*)alloc(S * 2);
  ushort* Kp   = (ushort*)alloc(S * 2);
  ushort* VtG  = (ushort*)alloc(S * 2);
  ushort* regA = (ushort*)alloc(S * 2);   // AOb
  ushort* XTb  = (ushort*)alloc(S * 2);   // then X2b
  ushort* X1b  = (ushort*)alloc(S * 2);
  ushort* Hb   = (ushort*)alloc((size_t)BNr * MLPH * 2);
  ushort* gcwT = (ushort*)alloc(65536 * 2);
  ushort* wqkvT= (ushort*)alloc(196608 * 2);
  ushort* woT  = (ushort*)alloc(65536 * 2);
  ushort* w1T  = (ushort*)alloc(262144 * 2);
  ushort* w2T  = (ushort*)alloc(262144 * 2);
  float* bqkv  = (float*)alloc(768 * 4);
  int* cnt_row = (int*)alloc(8192 * 4);
  int* cnt_col = (int*)alloc(8192 * 4);
  int* startA  = (int*)alloc(8200 * 4);
  int* cursor  = (int*)alloc(8192 * 4);
  int2* bucket = (int2*)alloc(Ee * 8);
  float* dis   = (float*)alloc(8192 * 4);
  int* flag    = (int*)alloc(256);

  ushort* AOb = regA;
  ushort* X2b = XTb;

  hipMemsetAsync(cnt_row, 0, 2 * 8192 * sizeof(int), stream);  // cnt_row+cnt_col contiguous

  // graph prep
  detect_kernel<<<1, 256, 0, stream>>>(ei, flag);
  count_kernel<<<Ee/256, 256, 0, stream>>>(ei, flag, cnt_row, cnt_col);
  scan_kernel<<<1, 256, 0, stream>>>(cnt_col, cnt_row, startA, cursor, dis);
  fill_kernel<<<Ee/256, 256, 0, stream>>>(ei, flag, dis, cursor, bucket);

  // weight converts
  tconv5_kernel<<<dim3(8,8,5), 256, 0, stream>>>(gc_w, wq, wk, wv, wo,
      gcwT, wqkvT, wqkvT + 65536, wqkvT + 131072, woT);
  tconv_kernel<<<dim3(32,8), 256, 0, stream>>>(w1, w1T, 256, 1024);
  tconv_kernel<<<dim3(8,32), 256, 0, stream>>>(w2, w2T, 1024, 256);
  bias_cat_kernel<<<3, 256, 0, stream>>>(bq, bk, bv, bqkv);

  const float qscale = 0.17677669529663687f * 1.4426950408889634f;  // log2e/sqrt(32)

  // xt = x @ gc_w (fp32 A staged+converted in-kernel, bf16 out)
  gemm64_bf16<1,1><<<dim3(Dd/64, BNr/64), 256, 0, stream>>>(
      x, gcwT, nullptr, nullptr, XTb, BNr, Dd, Dd);
  // GraphConv gather + residual + LN1
  gather_ln_kernel<<<BNr, 128, 0, stream>>>(XTb, bucket, startA,
                                            x, gc_b, g_gamma, g_beta, X1, X1b);
  // fused QKV, routed epilogue (Q pre-scaled; K packed; V transposed direct)
  gemm_bf16<3><<<dim3(768/64, BNr/128), 256, 0, stream>>>(
      X1b, wqkvT, bqkv, nullptr, nullptr, BNr, Dd, 768, qscale, Qp, Kp, VtG);
  // attention
  attn7_kernel<<<Bb*Hh*32, 256, 0, stream>>>(Qp, Kp, VtG, AOb);
  // out proj + LN2
  gemm64_bf16<0,0><<<dim3(Dd/64, BNr/64), 256, 0, stream>>>(
      AOb, woT, bo, PROJ, nullptr, BNr, Dd, Dd);
  add_ln_kernel<<<BNr, 256, 0, stream>>>(X1, PROJ, a_gamma, a_beta, X2, X2b);
  // MLP
  gemm_bf16<2><<<dim3(MLPH/64, BNr/128), 256, 0, stream>>>(
      X2b, w1T, b1, nullptr, Hb, BNr, Dd, MLPH, 1.0f, nullptr, nullptr, nullptr);
  gemm64_bf16<0,0><<<dim3(Dd/64, BNr/64), 256, 0, stream>>>(
      Hb, w2T, b2, MO, nullptr, BNr, MLPH, Dd);
  add_ln_kernel<<<BNr, 256, 0, stream>>>(X2, MO, m_gamma, m_beta, out, nullptr);
}